// Round 1
// baseline (4104.373 us; speedup 1.0000x reference)
//
#include <hip/hip_runtime.h>
#include <hip/hip_bf16.h>
#include <math.h>

#define N_NODES 20000
#define NHID    256
#define NOUT    128
#define HDIM    128
#define G3      384      // 3*H
#define NHID_E  256
#define T_SNAP  16
#define E_EDGES 320000
#define EP_EDGES 100000
#define BN_EPS  1e-5f

// ---------------------------------------------------------------------------
// CSR build: histogram -> per-snapshot exclusive scan -> scatter
// ---------------------------------------------------------------------------
__global__ void k_count(const int* __restrict__ rows, int* __restrict__ cnt) {
    int i = blockIdx.x * blockDim.x + threadIdx.x;
    if (i < T_SNAP * E_EDGES) {
        int t = i / E_EDGES;
        atomicAdd(&cnt[t * N_NODES + rows[i]], 1);
    }
}

// one block per snapshot; writes row_ptr[t][0..N] and resets cnt to cursors
__global__ void k_scan(int* __restrict__ cnt, int* __restrict__ row_ptr) {
    int t = blockIdx.x;
    __shared__ int sh[256];
    __shared__ int carry;
    if (threadIdx.x == 0) carry = 0;
    __syncthreads();
    int* c  = cnt + t * N_NODES;
    int* rp = row_ptr + t * (N_NODES + 1);
    for (int base = 0; base < N_NODES; base += 256) {
        int i = base + threadIdx.x;
        int v = (i < N_NODES) ? c[i] : 0;
        sh[threadIdx.x] = v;
        __syncthreads();
        #pragma unroll
        for (int off = 1; off < 256; off <<= 1) {
            int add = (threadIdx.x >= off) ? sh[threadIdx.x - off] : 0;
            __syncthreads();
            sh[threadIdx.x] += add;
            __syncthreads();
        }
        int excl = carry + sh[threadIdx.x] - v;
        if (i < N_NODES) { rp[i] = excl; c[i] = excl; }
        __syncthreads();
        if (threadIdx.x == 255) carry += sh[255];
        __syncthreads();
    }
    if (threadIdx.x == 0) rp[N_NODES] = carry;
}

__global__ void k_scatter(const int* __restrict__ rows, const int* __restrict__ cols,
                          const float* __restrict__ vals, int* __restrict__ cur,
                          int* __restrict__ col_s, float* __restrict__ val_s) {
    int i = blockIdx.x * blockDim.x + threadIdx.x;
    if (i < T_SNAP * E_EDGES) {
        int t = i / E_EDGES;
        int p = atomicAdd(&cur[t * N_NODES + rows[i]], 1);
        col_s[t * E_EDGES + p] = cols[i];
        val_s[t * E_EDGES + p] = vals[i];
    }
}

// ---------------------------------------------------------------------------
// SpMM: one block per output row, thread j accumulates column j. No atomics.
// ---------------------------------------------------------------------------
template<int D, bool RELU>
__global__ void k_spmm(const int* __restrict__ rp, const int* __restrict__ col_s,
                       const float* __restrict__ val_s, const float* __restrict__ X,
                       const float* __restrict__ bias, float* __restrict__ Y) {
    int row = blockIdx.x;
    int j = threadIdx.x;
    int s = rp[row], e = rp[row + 1];
    float acc = bias[j];
    for (int k = s; k < e; ++k) {
        int   c = col_s[k];
        float v = val_s[k];
        acc = fmaf(v, X[(size_t)c * D + j], acc);
    }
    if (RELU) acc = fmaxf(acc, 0.f);
    Y[(size_t)row * D + j] = acc;
}

// ---------------------------------------------------------------------------
// Simple fp32 tiled GEMM: C[M,Nc] = A[M,K] * op(B) (+bias), 64x64 tile, BK=16
// TRANSB: B is [Nc,K] row-major (use B^T). Requires K%16==0, Nc%64==0.
// ---------------------------------------------------------------------------
template<bool TRANSB, bool BIAS>
__global__ __launch_bounds__(256) void k_gemm(
        const float* __restrict__ A, int lda,
        const float* __restrict__ B, int ldb,
        const float* __restrict__ bias,
        float* __restrict__ C, int ldc,
        int M, int Nc, int K) {
    __shared__ float As[16][68];
    __shared__ float Bs[16][68];
    int tid = threadIdx.x;
    int tx = tid & 15, ty = tid >> 4;
    int m0 = blockIdx.y * 64, n0 = blockIdx.x * 64;

    int ar = tid >> 2;         // 0..63
    int ak = (tid & 3) << 2;   // 0,4,8,12

    float acc[4][4] = {};

    for (int k0 = 0; k0 < K; k0 += 16) {
        float4 av = make_float4(0.f, 0.f, 0.f, 0.f);
        int grow = m0 + ar;
        if (grow < M) av = *(const float4*)(A + (size_t)grow * lda + k0 + ak);
        As[ak + 0][ar] = av.x; As[ak + 1][ar] = av.y;
        As[ak + 2][ar] = av.z; As[ak + 3][ar] = av.w;
        if (!TRANSB) {
            int bk = tid >> 4;          // 0..15
            int bn = (tid & 15) << 2;   // 0..60
            float4 bv = *(const float4*)(B + (size_t)(k0 + bk) * ldb + n0 + bn);
            Bs[bk][bn + 0] = bv.x; Bs[bk][bn + 1] = bv.y;
            Bs[bk][bn + 2] = bv.z; Bs[bk][bn + 3] = bv.w;
        } else {
            float4 bv = *(const float4*)(B + (size_t)(n0 + ar) * ldb + k0 + ak);
            Bs[ak + 0][ar] = bv.x; Bs[ak + 1][ar] = bv.y;
            Bs[ak + 2][ar] = bv.z; Bs[ak + 3][ar] = bv.w;
        }
        __syncthreads();
        #pragma unroll
        for (int k = 0; k < 16; ++k) {
            float4 a = *(const float4*)&As[k][ty << 2];
            float4 b = *(const float4*)&Bs[k][tx << 2];
            float aa[4] = {a.x, a.y, a.z, a.w};
            float bb[4] = {b.x, b.y, b.z, b.w};
            #pragma unroll
            for (int i = 0; i < 4; ++i)
                #pragma unroll
                for (int j = 0; j < 4; ++j)
                    acc[i][j] = fmaf(aa[i], bb[j], acc[i][j]);
        }
        __syncthreads();
    }
    #pragma unroll
    for (int i = 0; i < 4; ++i) {
        int r = m0 + (ty << 2) + i;
        if (r < M) {
            #pragma unroll
            for (int j = 0; j < 4; ++j) {
                int c = n0 + (tx << 2) + j;
                float v = acc[i][j];
                if (BIAS) v += bias[c];
                C[(size_t)r * ldc + c] = v;
            }
        }
    }
}

// ---------------------------------------------------------------------------
// GRU pointwise: h = (1-z)*n + z*h
// ---------------------------------------------------------------------------
__global__ void k_gru(const float* __restrict__ GI, const float* __restrict__ GH,
                      float* __restrict__ h) {
    int i = blockIdx.x * blockDim.x + threadIdx.x;
    if (i >= N_NODES * HDIM) return;
    int n = i >> 7, j = i & 127;
    const float* gi = GI + (size_t)n * G3;
    const float* gh = GH + (size_t)n * G3;
    float r  = 1.f / (1.f + expf(-(gi[j]       + gh[j])));
    float z  = 1.f / (1.f + expf(-(gi[128 + j] + gh[128 + j])));
    float ng = tanhf(gi[256 + j] + r * gh[256 + j]);
    h[i] = (1.f - z) * ng + z * h[i];
}

// ---------------------------------------------------------------------------
// BatchNorm: column sums/sumsq then normalize
// ---------------------------------------------------------------------------
__global__ void k_bnstats(const float* __restrict__ h, float* __restrict__ stats) {
    int j = threadIdx.x;               // 0..127
    int r0 = blockIdx.x * 200;
    float s = 0.f, sq = 0.f;
    for (int r = r0; r < r0 + 200; ++r) {
        float v = h[(size_t)r * HDIM + j];
        s += v; sq += v * v;
    }
    atomicAdd(&stats[j], s);
    atomicAdd(&stats[128 + j], sq);
}

__global__ void k_bnapply(const float* __restrict__ h, const float* __restrict__ stats,
                          const float* __restrict__ gamma, const float* __restrict__ beta,
                          float* __restrict__ emb) {
    int i = blockIdx.x * blockDim.x + threadIdx.x;
    if (i >= N_NODES * HDIM) return;
    int j = i & 127;
    float mean = stats[j] * (1.f / N_NODES);
    float var  = stats[128 + j] * (1.f / N_NODES) - mean * mean;
    emb[i] = (h[i] - mean) * rsqrtf(var + BN_EPS) * gamma[j] + beta[j];
}

// ---------------------------------------------------------------------------
// Edge predictor: one wave per edge. hmid = relu(P[u]+Q[v]) (be1 folded in P),
// logits = hmid @ We2 + be2, then log_softmax over 2 classes.
// ---------------------------------------------------------------------------
__global__ __launch_bounds__(256) void k_edge(const int* __restrict__ edges,
        const float* __restrict__ P, const float* __restrict__ Q,
        const float* __restrict__ We2, const float* __restrict__ be2,
        float* __restrict__ out) {
    int e = blockIdx.x * 4 + (threadIdx.x >> 6);
    int lane = threadIdx.x & 63;
    if (e >= EP_EDGES) return;
    int u = edges[e];
    int v = edges[EP_EDGES + e];
    const float* p = P + (size_t)u * NHID_E;
    const float* q = Q + (size_t)v * NHID_E;
    float l0 = 0.f, l1 = 0.f;
    #pragma unroll
    for (int jj = 0; jj < 4; ++jj) {
        int j = lane + jj * 64;
        float hm = fmaxf(p[j] + q[j], 0.f);
        float2 w = ((const float2*)We2)[j];
        l0 = fmaf(hm, w.x, l0);
        l1 = fmaf(hm, w.y, l1);
    }
    #pragma unroll
    for (int off = 32; off > 0; off >>= 1) {
        l0 += __shfl_down(l0, off);
        l1 += __shfl_down(l1, off);
    }
    if (lane == 0) {
        l0 += be2[0]; l1 += be2[1];
        float m = fmaxf(l0, l1);
        float lse = m + logf(expf(l0 - m) + expf(l1 - m));
        out[(size_t)e * 2 + 0] = l0 - lse;
        out[(size_t)e * 2 + 1] = l1 - lse;
    }
}

// ---------------------------------------------------------------------------
extern "C" void kernel_launch(void* const* d_in, const int* in_sizes, int n_in,
                              void* d_out, int out_size, void* d_ws, size_t ws_size,
                              hipStream_t stream) {
    const int*   adj_rows = (const int*)  d_in[0];
    const int*   adj_cols = (const int*)  d_in[1];
    const float* adj_vals = (const float*)d_in[2];
    const int*   edges    = (const int*)  d_in[3];
    const float* W0   = (const float*)d_in[4];
    const float* b0   = (const float*)d_in[5];
    const float* W1   = (const float*)d_in[6];
    const float* b1   = (const float*)d_in[7];
    const float* W_ih = (const float*)d_in[8];
    const float* W_hh = (const float*)d_in[9];
    const float* b_ih = (const float*)d_in[10];
    const float* b_hh = (const float*)d_in[11];
    const float* gamma = (const float*)d_in[12];
    const float* beta  = (const float*)d_in[13];
    const float* We1  = (const float*)d_in[14];
    const float* be1  = (const float*)d_in[15];
    const float* We2  = (const float*)d_in[16];
    const float* be2  = (const float*)d_in[17];
    float* out = (float*)d_out;

    char* ws = (char*)d_ws;
    size_t off = 0;
    auto alloc = [&](size_t bytes) -> void* {
        void* p = ws + off;
        off += (bytes + 255) & ~(size_t)255;
        return p;
    };
    float* h       = (float*)alloc((size_t)N_NODES * HDIM * 4);
    int*   row_ptr = (int*)  alloc((size_t)T_SNAP * (N_NODES + 1) * 4);
    int*   cnt     = (int*)  alloc((size_t)T_SNAP * N_NODES * 4);
    int*   col_s   = (int*)  alloc((size_t)T_SNAP * E_EDGES * 4);
    float* val_s   = (float*)alloc((size_t)T_SNAP * E_EDGES * 4);
    float* X0      = (float*)alloc((size_t)N_NODES * NHID * 4);
    float* Y       = (float*)alloc((size_t)N_NODES * NOUT * 4);
    float* X2      = (float*)alloc((size_t)N_NODES * NOUT * 4);
    float* GI      = (float*)alloc((size_t)N_NODES * G3 * 4);
    float* GH      = (float*)alloc((size_t)N_NODES * G3 * 4);
    float* stats   = (float*)alloc(256 * 4);
    if (off > ws_size) return;   // visible failure instead of corruption

    float* emb = X0;   // X0 dead after the GCN/GRU loop
    float* P   = GI;   // GI/GH dead after the loop
    float* Q   = GH;

    hipMemsetAsync(cnt,   0, (size_t)T_SNAP * N_NODES * 4, stream);
    hipMemsetAsync(h,     0, (size_t)N_NODES * HDIM * 4, stream);
    hipMemsetAsync(stats, 0, 256 * 4, stream);

    // ---- CSR build for all snapshots ----
    int te_blocks = (T_SNAP * E_EDGES + 255) / 256;
    k_count  <<<te_blocks, 256, 0, stream>>>(adj_rows, cnt);
    k_scan   <<<T_SNAP,    256, 0, stream>>>(cnt, row_ptr);
    k_scatter<<<te_blocks, 256, 0, stream>>>(adj_rows, adj_cols, adj_vals, cnt, col_s, val_s);

    // ---- GCN + GRU over snapshots ----
    for (int t = 0; t < T_SNAP; ++t) {
        const int*   rp = row_ptr + (size_t)t * (N_NODES + 1);
        const int*   cs = col_s + (size_t)t * E_EDGES;
        const float* vs = val_s + (size_t)t * E_EDGES;

        // layer0: X0 = relu(A @ W0 + b0)    [N, 256]
        k_spmm<NHID, true><<<N_NODES, NHID, 0, stream>>>(rp, cs, vs, W0, b0, X0);
        // Y = X0 @ W1                        [N, 128]
        k_gemm<false, false><<<dim3(NOUT / 64, (N_NODES + 63) / 64), 256, 0, stream>>>(
            X0, NHID, W1, NOUT, nullptr, Y, NOUT, N_NODES, NOUT, NHID);
        // layer1: X2 = A @ Y + b1            [N, 128]
        k_spmm<NOUT, false><<<N_NODES, NOUT, 0, stream>>>(rp, cs, vs, Y, b1, X2);

        // GRU gates
        k_gemm<true, true><<<dim3(G3 / 64, (N_NODES + 63) / 64), 256, 0, stream>>>(
            X2, NOUT, W_ih, NOUT, b_ih, GI, G3, N_NODES, G3, NOUT);
        k_gemm<true, true><<<dim3(G3 / 64, (N_NODES + 63) / 64), 256, 0, stream>>>(
            h, HDIM, W_hh, HDIM, b_hh, GH, G3, N_NODES, G3, HDIM);
        k_gru<<<(N_NODES * HDIM + 255) / 256, 256, 0, stream>>>(GI, GH, h);
    }

    // ---- BatchNorm (training mode, biased var) ----
    k_bnstats<<<100, 128, 0, stream>>>(h, stats);
    k_bnapply<<<(N_NODES * HDIM + 255) / 256, 256, 0, stream>>>(h, stats, gamma, beta, emb);

    // ---- Edge MLP: P = emb @ We1_top + be1, Q = emb @ We1_bot ----
    k_gemm<false, true><<<dim3(NHID_E / 64, (N_NODES + 63) / 64), 256, 0, stream>>>(
        emb, HDIM, We1, NHID_E, be1, P, NHID_E, N_NODES, NHID_E, HDIM);
    k_gemm<false, false><<<dim3(NHID_E / 64, (N_NODES + 63) / 64), 256, 0, stream>>>(
        emb, HDIM, We1 + (size_t)HDIM * NHID_E, NHID_E, nullptr, Q, NHID_E, N_NODES, NHID_E, HDIM);

    k_edge<<<(EP_EDGES + 3) / 4, 256, 0, stream>>>(edges, P, Q, We2, be2, out);
}

// Round 2
// 1981.773 us; speedup vs baseline: 2.0711x; 2.0711x over previous
//
#include <hip/hip_runtime.h>
#include <math.h>

#define N_NODES 20000
#define NHID    256
#define NOUT    128
#define HDIM    128
#define NHID_E  256
#define T_SNAP  16
#define E_EDGES 320000
#define EP_EDGES 100000
#define BN_EPS  1e-5f

typedef unsigned short u16;
typedef __attribute__((ext_vector_type(8))) short bf16x8;
typedef __attribute__((ext_vector_type(4))) float f32x4;

__device__ __forceinline__ u16 f2b(float f) {
    unsigned u = __float_as_uint(f);
    u += 0x7FFFu + ((u >> 16) & 1u);
    return (u16)(u >> 16);
}
__device__ __forceinline__ float b2f(u16 s) { return __uint_as_float(((unsigned)s) << 16); }

// ---------------------------------------------------------------------------
// CSR build
// ---------------------------------------------------------------------------
__global__ void k_count(const int* __restrict__ rows, int* __restrict__ cnt) {
    int t = blockIdx.y;
    int i = blockIdx.x * 256 + threadIdx.x;
    atomicAdd(&cnt[t * N_NODES + rows[(size_t)t * E_EDGES + i]], 1);
}

__global__ void k_scan(int* __restrict__ cnt, int* __restrict__ row_ptr) {
    int t = blockIdx.x;
    __shared__ int sh[256];
    __shared__ int carry;
    if (threadIdx.x == 0) carry = 0;
    __syncthreads();
    int* c  = cnt + t * N_NODES;
    int* rp = row_ptr + t * (N_NODES + 1);
    for (int base = 0; base < N_NODES; base += 256) {
        int i = base + threadIdx.x;
        int v = (i < N_NODES) ? c[i] : 0;
        sh[threadIdx.x] = v;
        __syncthreads();
        #pragma unroll
        for (int off = 1; off < 256; off <<= 1) {
            int add = (threadIdx.x >= off) ? sh[threadIdx.x - off] : 0;
            __syncthreads();
            sh[threadIdx.x] += add;
            __syncthreads();
        }
        int excl = carry + sh[threadIdx.x] - v;
        if (i < N_NODES) { rp[i] = excl; c[i] = excl; }
        __syncthreads();
        if (threadIdx.x == 255) carry += sh[255];
        __syncthreads();
    }
    if (threadIdx.x == 0) rp[N_NODES] = carry;
}

__global__ void k_scatter(const int* __restrict__ rows, const int* __restrict__ cols,
                          const float* __restrict__ vals, int* __restrict__ cur,
                          uint2* __restrict__ colval) {
    int t = blockIdx.y;
    int i = blockIdx.x * 256 + threadIdx.x;
    size_t gi = (size_t)t * E_EDGES + i;
    int p = atomicAdd(&cur[t * N_NODES + rows[gi]], 1);
    uint2 pv;
    pv.x = (unsigned)cols[gi];
    pv.y = __float_as_uint(vals[gi]);
    colval[(size_t)t * E_EDGES + p] = pv;
}

// ---------------------------------------------------------------------------
// Conversions
// ---------------------------------------------------------------------------
__global__ void k_cvt(const float* __restrict__ in, u16* __restrict__ out, int n4) {
    int i = blockIdx.x * 256 + threadIdx.x;
    if (i < n4) {
        float4 v = ((const float4*)in)[i];
        ushort4 o;
        o.x = f2b(v.x); o.y = f2b(v.y); o.z = f2b(v.z); o.w = f2b(v.w);
        ((ushort4*)out)[i] = o;
    }
}

// out[n*Kr + k] = in[k*Nc + n]   (in: [Kr][Nc] -> out: [Nc][Kr])
__global__ void k_tcvt(const float* __restrict__ in, u16* __restrict__ out, int Kr, int Nc) {
    int i = blockIdx.x * 256 + threadIdx.x;
    if (i < Kr * Nc) {
        int k = i / Nc, n = i - k * Nc;
        out[(size_t)n * Kr + k] = f2b(in[i]);
    }
}

// Bg[512][256]: interleaved gate weights over concat(x,h).
// row rr: c=rr>>4, u=rr&15, g=c&3, jj=(c>>2)*16+u
__global__ void k_build_bg(const float* __restrict__ Wih, const float* __restrict__ Whh,
                           u16* __restrict__ Bg) {
    int i = blockIdx.x * 256 + threadIdx.x;
    if (i >= 512 * 256) return;
    int rr = i >> 8, k = i & 255;
    int c = rr >> 4, u = rr & 15, g = c & 3, jj = ((c >> 2) << 4) + u;
    float v;
    if (g == 0)      v = (k < 128) ? Wih[(size_t)jj * 128 + k]         : Whh[(size_t)jj * 128 + k - 128];
    else if (g == 1) v = (k < 128) ? Wih[(size_t)(128 + jj) * 128 + k] : Whh[(size_t)(128 + jj) * 128 + k - 128];
    else if (g == 2) v = (k < 128) ? Wih[(size_t)(256 + jj) * 128 + k] : 0.f;
    else             v = (k < 128) ? 0.f : Whh[(size_t)(256 + jj) * 128 + k - 128];
    Bg[i] = f2b(v);
}

__global__ void k_build_bgb(const float* __restrict__ bih, const float* __restrict__ bhh,
                            float* __restrict__ bgb) {
    int rr = blockIdx.x * 256 + threadIdx.x;
    if (rr >= 512) return;
    int c = rr >> 4, u = rr & 15, g = c & 3, jj = ((c >> 2) << 4) + u;
    float v;
    if (g == 0)      v = bih[jj] + bhh[jj];
    else if (g == 1) v = bih[128 + jj] + bhh[128 + jj];
    else if (g == 2) v = bih[256 + jj];
    else             v = bhh[256 + jj];
    bgb[rr] = v;
}

// ---------------------------------------------------------------------------
// Batched SpMM over BT snapshots: grid (N_NODES, BT), 64 threads, V=D/64 cols/thread
// ---------------------------------------------------------------------------
template<int D, bool RELU>
__global__ void k_spmm_all(const int* __restrict__ row_ptr_all, const uint2* __restrict__ colval_all,
                           int t0, const u16* __restrict__ X, size_t xtstride,
                           const float* __restrict__ bias, u16* __restrict__ Out) {
    constexpr int V = D / 64;
    int row = blockIdx.x, tl = blockIdx.y, t = t0 + tl, j = threadIdx.x;
    const int*   rp = row_ptr_all + (size_t)t * (N_NODES + 1);
    const uint2* cv = colval_all + (size_t)t * E_EDGES;
    const u16*   Xt = X + xtstride * tl;
    float acc[V];
    #pragma unroll
    for (int i = 0; i < V; ++i) acc[i] = bias[j * V + i];
    int s = rp[row], e = rp[row + 1];
    for (int k = s; k < e; ++k) {
        uint2 a = cv[k];
        float va = __uint_as_float(a.y);
        const u16* xr = Xt + (size_t)a.x * D + j * V;
        if constexpr (V == 4) {
            ushort4 x = *(const ushort4*)xr;
            acc[0] = fmaf(va, b2f(x.x), acc[0]);
            acc[1] = fmaf(va, b2f(x.y), acc[1]);
            acc[2] = fmaf(va, b2f(x.z), acc[2]);
            acc[3] = fmaf(va, b2f(x.w), acc[3]);
        } else {
            ushort2 x = *(const ushort2*)xr;
            acc[0] = fmaf(va, b2f(x.x), acc[0]);
            acc[1] = fmaf(va, b2f(x.y), acc[1]);
        }
    }
    u16* o = Out + ((size_t)tl * N_NODES + row) * D + j * V;
    if constexpr (V == 4) {
        ushort4 ov;
        float v0 = RELU ? fmaxf(acc[0], 0.f) : acc[0];
        float v1 = RELU ? fmaxf(acc[1], 0.f) : acc[1];
        float v2 = RELU ? fmaxf(acc[2], 0.f) : acc[2];
        float v3 = RELU ? fmaxf(acc[3], 0.f) : acc[3];
        ov.x = f2b(v0); ov.y = f2b(v1); ov.z = f2b(v2); ov.w = f2b(v3);
        *(ushort4*)o = ov;
    } else {
        ushort2 ov;
        float v0 = RELU ? fmaxf(acc[0], 0.f) : acc[0];
        float v1 = RELU ? fmaxf(acc[1], 0.f) : acc[1];
        ov.x = f2b(v0); ov.y = f2b(v1);
        *(ushort2*)o = ov;
    }
}

// ---------------------------------------------------------------------------
// bf16 MFMA GEMM: C[M,Nc] = A[M,K] @ B^T (B stored [Nc,ldb] bf16), out bf16.
// Block: 256 thr / 4 waves, tile 64(M) x 128(N). grid = (Nc/128, ceil(M/64)).
// ---------------------------------------------------------------------------
template<int KC, bool BIAS>
__global__ __launch_bounds__(256) void k_mgemm(
        const u16* __restrict__ A, const u16* __restrict__ B, int ldb,
        const float* __restrict__ bias, u16* __restrict__ C, int ldc, int M) {
    constexpr int K = KC * 32;
    __shared__ bf16x8 frag[8 * KC * 64];
    int tid = threadIdx.x, lane = tid & 63, wave = tid >> 6;
    int m0 = blockIdx.y * 64, n0 = blockIdx.x * 128;

    for (int f = wave; f < 8 * KC; f += 4) {
        int nl = f / KC, kc = f % KC;
        frag[f * 64 + lane] = *(const bf16x8*)(B + (size_t)(n0 + nl * 16 + (lane & 15)) * ldb
                                               + kc * 32 + ((lane >> 4) << 3));
    }
    __syncthreads();

    int arow = m0 + wave * 16 + (lane & 15);
    bool rowok = arow < M;
    const u16* ap = A + (size_t)arow * K + ((lane >> 4) << 3);
    bf16x8 zf = {0, 0, 0, 0, 0, 0, 0, 0};
    bf16x8 af[KC];
    #pragma unroll
    for (int kc = 0; kc < KC; ++kc)
        af[kc] = rowok ? *(const bf16x8*)(ap + kc * 32) : zf;

    f32x4 acc[8] = {};
    #pragma unroll
    for (int kc = 0; kc < KC; ++kc)
        #pragma unroll
        for (int nl = 0; nl < 8; ++nl)
            acc[nl] = __builtin_amdgcn_mfma_f32_16x16x32_bf16(
                af[kc], frag[(nl * KC + kc) * 64 + lane], acc[nl], 0, 0, 0);

    int r0 = m0 + wave * 16 + ((lane >> 4) << 2);
    #pragma unroll
    for (int nl = 0; nl < 8; ++nl) {
        int col = n0 + nl * 16 + (lane & 15);
        float bv = BIAS ? bias[col] : 0.f;
        #pragma unroll
        for (int r = 0; r < 4; ++r) {
            int row = r0 + r;
            if (row < M) C[(size_t)row * ldc + col] = f2b(acc[nl][r] + bv);
        }
    }
}

// ---------------------------------------------------------------------------
// Fused GRU step: gates = [X2_t | h] @ Bg^T (+bgb), epilogue does GRU pointwise.
// Bg interleave => acc[4*hb+g] holds gate g for hidden unit jj in SAME lane/reg.
// grid (4, 313). Reads Hbf_in, writes H (fp32, disjoint cols) + Hbf_out.
// ---------------------------------------------------------------------------
__global__ __launch_bounds__(256) void k_gru_gemm(
        const u16* __restrict__ X2t, const u16* __restrict__ HbfIn,
        const u16* __restrict__ Bg, const float* __restrict__ bgb,
        float* __restrict__ H, u16* __restrict__ HbfOut) {
    __shared__ bf16x8 frag[64 * 64];
    int tid = threadIdx.x, lane = tid & 63, wave = tid >> 6;
    int m0 = blockIdx.y * 64, n0 = blockIdx.x * 128;

    for (int f = wave; f < 64; f += 4) {
        int nl = f >> 3, kc = f & 7;
        frag[f * 64 + lane] = *(const bf16x8*)(Bg + (size_t)(n0 + nl * 16 + (lane & 15)) * 256
                                               + kc * 32 + ((lane >> 4) << 3));
    }
    __syncthreads();

    int arow = m0 + wave * 16 + (lane & 15);
    bool rowok = arow < N_NODES;
    bf16x8 zf = {0, 0, 0, 0, 0, 0, 0, 0};
    const u16* a1 = X2t   + (size_t)arow * 128 + ((lane >> 4) << 3);
    const u16* a2 = HbfIn + (size_t)arow * 128 + ((lane >> 4) << 3);
    bf16x8 af[8];
    #pragma unroll
    for (int kc = 0; kc < 4; ++kc) af[kc]     = rowok ? *(const bf16x8*)(a1 + kc * 32) : zf;
    #pragma unroll
    for (int kc = 0; kc < 4; ++kc) af[4 + kc] = rowok ? *(const bf16x8*)(a2 + kc * 32) : zf;

    f32x4 acc[8] = {};
    #pragma unroll
    for (int kc = 0; kc < 8; ++kc)
        #pragma unroll
        for (int nl = 0; nl < 8; ++nl)
            acc[nl] = __builtin_amdgcn_mfma_f32_16x16x32_bf16(
                af[kc], frag[(nl * 8 + kc) * 64 + lane], acc[nl], 0, 0, 0);

    int rbase = m0 + wave * 16 + ((lane >> 4) << 2);
    #pragma unroll
    for (int hb = 0; hb < 2; ++hb) {
        int jj = (2 * blockIdx.x + hb) * 16 + (lane & 15);
        float br = bgb[n0 + (4 * hb + 0) * 16 + (lane & 15)];
        float bz = bgb[n0 + (4 * hb + 1) * 16 + (lane & 15)];
        float bi = bgb[n0 + (4 * hb + 2) * 16 + (lane & 15)];
        float bh = bgb[n0 + (4 * hb + 3) * 16 + (lane & 15)];
        #pragma unroll
        for (int r = 0; r < 4; ++r) {
            int row = rbase + r;
            if (row >= N_NODES) continue;
            float rg = acc[4 * hb + 0][r] + br;
            float zg = acc[4 * hb + 1][r] + bz;
            float ig = acc[4 * hb + 2][r] + bi;
            float hg = acc[4 * hb + 3][r] + bh;
            rg = 1.f / (1.f + expf(-rg));
            zg = 1.f / (1.f + expf(-zg));
            float ng = tanhf(ig + rg * hg);
            size_t idx = (size_t)row * HDIM + jj;
            float ho = H[idx];
            float hn = (1.f - zg) * ng + zg * ho;
            H[idx] = hn;
            HbfOut[idx] = f2b(hn);
        }
    }
}

// ---------------------------------------------------------------------------
// BatchNorm
// ---------------------------------------------------------------------------
__global__ void k_bnstats(const float* __restrict__ h, float* __restrict__ stats) {
    int j = threadIdx.x;
    int r0 = blockIdx.x * 200;
    float s = 0.f, sq = 0.f;
    for (int r = r0; r < r0 + 200; ++r) {
        float v = h[(size_t)r * HDIM + j];
        s += v; sq += v * v;
    }
    atomicAdd(&stats[j], s);
    atomicAdd(&stats[128 + j], sq);
}

__global__ void k_bnapply(const float* __restrict__ h, const float* __restrict__ stats,
                          const float* __restrict__ gamma, const float* __restrict__ beta,
                          u16* __restrict__ emb) {
    int i = blockIdx.x * 256 + threadIdx.x;
    if (i >= N_NODES * HDIM) return;
    int j = i & 127;
    float mean = stats[j] * (1.f / N_NODES);
    float var  = stats[128 + j] * (1.f / N_NODES) - mean * mean;
    emb[i] = f2b((h[i] - mean) * rsqrtf(var + BN_EPS) * gamma[j] + beta[j]);
}

// ---------------------------------------------------------------------------
// Edge predictor: one wave per edge
// ---------------------------------------------------------------------------
__global__ __launch_bounds__(256) void k_edge(const int* __restrict__ edges,
        const u16* __restrict__ P, const u16* __restrict__ Q,
        const float* __restrict__ We2, const float* __restrict__ be2,
        float* __restrict__ out) {
    int e = blockIdx.x * 4 + (threadIdx.x >> 6);
    int lane = threadIdx.x & 63;
    if (e >= EP_EDGES) return;
    int u = edges[e];
    int v = edges[EP_EDGES + e];
    ushort4 pv = *(const ushort4*)(P + (size_t)u * NHID_E + lane * 4);
    ushort4 qv = *(const ushort4*)(Q + (size_t)v * NHID_E + lane * 4);
    const float4* w = (const float4*)(We2 + lane * 8);
    float4 w0 = w[0], w1 = w[1];
    float h0 = fmaxf(b2f(pv.x) + b2f(qv.x), 0.f);
    float h1 = fmaxf(b2f(pv.y) + b2f(qv.y), 0.f);
    float h2 = fmaxf(b2f(pv.z) + b2f(qv.z), 0.f);
    float h3 = fmaxf(b2f(pv.w) + b2f(qv.w), 0.f);
    float l0 = h0 * w0.x + h1 * w0.z + h2 * w1.x + h3 * w1.z;
    float l1 = h0 * w0.y + h1 * w0.w + h2 * w1.y + h3 * w1.w;
    #pragma unroll
    for (int off = 32; off > 0; off >>= 1) {
        l0 += __shfl_down(l0, off);
        l1 += __shfl_down(l1, off);
    }
    if (lane == 0) {
        l0 += be2[0]; l1 += be2[1];
        float m = fmaxf(l0, l1);
        float lse = m + logf(expf(l0 - m) + expf(l1 - m));
        out[(size_t)e * 2 + 0] = l0 - lse;
        out[(size_t)e * 2 + 1] = l1 - lse;
    }
}

// ---------------------------------------------------------------------------
extern "C" void kernel_launch(void* const* d_in, const int* in_sizes, int n_in,
                              void* d_out, int out_size, void* d_ws, size_t ws_size,
                              hipStream_t stream) {
    const int*   adj_rows = (const int*)  d_in[0];
    const int*   adj_cols = (const int*)  d_in[1];
    const float* adj_vals = (const float*)d_in[2];
    const int*   edges    = (const int*)  d_in[3];
    const float* W0   = (const float*)d_in[4];
    const float* b0   = (const float*)d_in[5];
    const float* W1   = (const float*)d_in[6];
    const float* b1   = (const float*)d_in[7];
    const float* W_ih = (const float*)d_in[8];
    const float* W_hh = (const float*)d_in[9];
    const float* b_ih = (const float*)d_in[10];
    const float* b_hh = (const float*)d_in[11];
    const float* gamma = (const float*)d_in[12];
    const float* beta  = (const float*)d_in[13];
    const float* We1  = (const float*)d_in[14];
    const float* be1  = (const float*)d_in[15];
    const float* We2  = (const float*)d_in[16];
    const float* be2  = (const float*)d_in[17];
    float* out = (float*)d_out;

    char* ws = (char*)d_ws;
    size_t off = 0;
    auto alloc = [&](size_t bytes) -> void* {
        void* p = ws + off;
        off += (bytes + 255) & ~(size_t)255;
        return p;
    };
    int*   row_ptr = (int*)  alloc((size_t)T_SNAP * (N_NODES + 1) * 4);
    int*   cnt     = (int*)  alloc((size_t)T_SNAP * N_NODES * 4);
    uint2* colval  = (uint2*)alloc((size_t)T_SNAP * E_EDGES * 8);
    u16*   W0_bf   = (u16*)  alloc((size_t)N_NODES * NHID * 2);
    u16*   W1t     = (u16*)  alloc((size_t)NOUT * NHID * 2);
    u16*   We1T    = (u16*)  alloc((size_t)NHID_E * 256 * 2);
    u16*   Bg      = (u16*)  alloc((size_t)512 * 256 * 2);
    float* bgb     = (float*)alloc(512 * 4);
    float* h       = (float*)alloc((size_t)N_NODES * HDIM * 4);
    u16*   h_bfA   = (u16*)  alloc((size_t)N_NODES * HDIM * 2);
    u16*   h_bfB   = (u16*)  alloc((size_t)N_NODES * HDIM * 2);
    float* stats   = (float*)alloc(256 * 4);
    u16*   X2_all  = (u16*)  alloc((size_t)T_SNAP * N_NODES * NOUT * 2);
    size_t base_end = off;

    // pick largest batch of snapshots whose staging fits
    int BT = 8;
    while (BT > 1 && base_end + (size_t)BT * N_NODES * (NHID + NOUT) * 2 > ws_size) BT >>= 1;
    u16* X0_b = (u16*)alloc((size_t)BT * N_NODES * NHID * 2);
    u16* Y_b  = (u16*)alloc((size_t)BT * N_NODES * NOUT * 2);
    if (off > ws_size) return;   // visible failure instead of corruption

    // emb/P/Q alias the (then-dead) X2_all region
    u16* emb = X2_all;
    u16* P   = X2_all + (size_t)N_NODES * HDIM;                              // +2.56M elems
    u16* Q   = P + (size_t)N_NODES * NHID_E;

    hipMemsetAsync(cnt,   0, (size_t)T_SNAP * N_NODES * 4, stream);
    hipMemsetAsync(stats, 0, 256 * 4, stream);
    hipMemsetAsync(h,     0, (size_t)N_NODES * HDIM * 4, stream);
    hipMemsetAsync(h_bfA, 0, (size_t)N_NODES * HDIM * 2, stream);

    // ---- CSR build ----
    dim3 teg(E_EDGES / 256, T_SNAP);
    k_count  <<<teg, 256, 0, stream>>>(adj_rows, cnt);
    k_scan   <<<T_SNAP, 256, 0, stream>>>(cnt, row_ptr);
    k_scatter<<<teg, 256, 0, stream>>>(adj_rows, adj_cols, adj_vals, cnt, colval);

    // ---- weight conversions ----
    k_cvt      <<<(N_NODES * NHID / 4 + 255) / 256, 256, 0, stream>>>(W0, W0_bf, N_NODES * NHID / 4);
    k_tcvt     <<<(NHID * NOUT + 255) / 256,   256, 0, stream>>>(W1, W1t, NHID, NOUT);
    k_tcvt     <<<(256 * NHID_E + 255) / 256,  256, 0, stream>>>(We1, We1T, 256, NHID_E);
    k_build_bg <<<(512 * 256 + 255) / 256,     256, 0, stream>>>(W_ih, W_hh, Bg);
    k_build_bgb<<<2, 256, 0, stream>>>(b_ih, b_hh, bgb);

    // ---- batched GCN: layer0 spmm -> X0@W1 -> layer1 spmm ----
    for (int g = 0; g < T_SNAP; g += BT) {
        k_spmm_all<NHID, true><<<dim3(N_NODES, BT), 64, 0, stream>>>(
            row_ptr, colval, g, W0_bf, 0, b0, X0_b);
        int M = BT * N_NODES;
        k_mgemm<8, false><<<dim3(1, (M + 63) / 64), 256, 0, stream>>>(
            X0_b, W1t, NHID, nullptr, Y_b, NOUT, M);
        k_spmm_all<NOUT, false><<<dim3(N_NODES, BT), 64, 0, stream>>>(
            row_ptr, colval, g, Y_b, (size_t)N_NODES * NOUT, b1,
            X2_all + (size_t)g * N_NODES * NOUT);
    }

    // ---- GRU: one fused GEMM+pointwise per snapshot ----
    for (int t = 0; t < T_SNAP; ++t) {
        const u16* hin  = (t & 1) ? h_bfB : h_bfA;
        u16*       hout = (t & 1) ? h_bfA : h_bfB;
        k_gru_gemm<<<dim3(4, (N_NODES + 63) / 64), 256, 0, stream>>>(
            X2_all + (size_t)t * N_NODES * NOUT, hin, Bg, bgb, h, hout);
    }

    // ---- BatchNorm ----
    k_bnstats<<<100, 128, 0, stream>>>(h, stats);
    k_bnapply<<<(N_NODES * HDIM + 255) / 256, 256, 0, stream>>>(h, stats, gamma, beta, emb);

    // ---- Edge MLP precompute + predictor ----
    k_mgemm<4, true><<<dim3(2, (N_NODES + 63) / 64), 256, 0, stream>>>(
        emb, We1T, 256, be1, P, NHID_E, N_NODES);
    k_mgemm<4, false><<<dim3(2, (N_NODES + 63) / 64), 256, 0, stream>>>(
        emb, We1T + 128, 256, nullptr, Q, NHID_E, N_NODES);
    k_edge<<<(EP_EDGES + 3) / 4, 256, 0, stream>>>(edges, P, Q, We2, be2, out);
}

// Round 3
// 1460.072 us; speedup vs baseline: 2.8111x; 1.3573x over previous
//
#include <hip/hip_runtime.h>
#include <math.h>

#define N_NODES 20000
#define NHID    256
#define NOUT    128
#define HDIM    128
#define NHID_E  256
#define T_SNAP  16
#define E_EDGES 320000
#define EP_EDGES 100000
#define BN_EPS  1e-5f

#define BROWS 128                    // rows per bucket
#define NBUCK 157                    // ceil(N_NODES / BROWS)
#define BCAP  4096                   // staging capacity per bucket

typedef unsigned short u16;
typedef __attribute__((ext_vector_type(8))) short bf16x8;
typedef __attribute__((ext_vector_type(4))) float f32x4;

__device__ __forceinline__ u16 f2b(float f) {
    unsigned u = __float_as_uint(f);
    u += 0x7FFFu + ((u >> 16) & 1u);
    return (u16)(u >> 16);
}
__device__ __forceinline__ float b2f(u16 s) { return __uint_as_float(((unsigned)s) << 16); }

// ---------------------------------------------------------------------------
// CSR build v2, phase 1: block-local counting sort by bucket, append runs.
// Entry packing: x = col | ((row&127)<<15)  (col < 2^15), y = val bits.
// ---------------------------------------------------------------------------
__global__ __launch_bounds__(256) void k_p1(const int* __restrict__ rows,
        const int* __restrict__ cols, const float* __restrict__ vals,
        int* __restrict__ bcnt, uint2* __restrict__ staging,
        uint4* __restrict__ ovf, int* __restrict__ ovf_cnt) {
    int t = blockIdx.y;
    int base = blockIdx.x * 4096;
    int tid = threadIdx.x;
    __shared__ int hist[256], sc[256], excl[256], cursor[256], gbase[256];
    __shared__ uint2 ebuf[4096];
    __shared__ u16 ebuck[4096];
    hist[tid] = 0;
    __syncthreads();
    const int*   rt = rows + (size_t)t * E_EDGES;
    const int*   ct = cols + (size_t)t * E_EDGES;
    const float* vt = vals + (size_t)t * E_EDGES;
    #pragma unroll
    for (int k = 0; k < 16; ++k) {
        int i = base + k * 256 + tid;
        if (i < E_EDGES) atomicAdd(&hist[rt[i] >> 7], 1);
    }
    __syncthreads();
    sc[tid] = hist[tid];
    __syncthreads();
    for (int off = 1; off < 256; off <<= 1) {
        int add = (tid >= off) ? sc[tid - off] : 0;
        __syncthreads();
        sc[tid] += add;
        __syncthreads();
    }
    excl[tid]   = sc[tid] - hist[tid];
    cursor[tid] = sc[tid] - hist[tid];
    __syncthreads();
    #pragma unroll
    for (int k = 0; k < 16; ++k) {
        int i = base + k * 256 + tid;
        if (i < E_EDGES) {
            int r = rt[i];
            int b = r >> 7;
            int s = atomicAdd(&cursor[b], 1);
            uint2 e;
            e.x = (unsigned)ct[i] | ((unsigned)(r & 127) << 15);
            e.y = __float_as_uint(vt[i]);
            ebuf[s]  = e;
            ebuck[s] = (u16)b;
        }
    }
    __syncthreads();
    if (hist[tid] > 0) gbase[tid] = atomicAdd(&bcnt[t * NBUCK + tid], hist[tid]);
    __syncthreads();
    int nvalid = min(4096, E_EDGES - base);
    for (int s = tid; s < nvalid; s += 256) {
        int b = ebuck[s];
        int g = gbase[b] + (s - excl[b]);
        if (g < BCAP) {
            staging[((size_t)t * NBUCK + b) * BCAP + g] = ebuf[s];
        } else {
            int o = atomicAdd(ovf_cnt, 1);
            uint4 e4; e4.x = (unsigned)(t * NBUCK + b); e4.y = ebuf[s].x; e4.z = ebuf[s].y; e4.w = 0;
            ovf[o] = e4;
        }
    }
}

// phase 2a: exclusive scan of all bucket counts (2512 values), one block
__global__ void k_bscan(const int* __restrict__ bcnt, int* __restrict__ bbase,
                        int* __restrict__ row_ptr) {
    __shared__ int sh[256];
    __shared__ int carry;
    int tid = threadIdx.x;
    if (tid == 0) carry = 0;
    __syncthreads();
    for (int b0 = 0; b0 < T_SNAP * NBUCK; b0 += 256) {
        int i = b0 + tid;
        int v = (i < T_SNAP * NBUCK) ? bcnt[i] : 0;
        sh[tid] = v;
        __syncthreads();
        for (int off = 1; off < 256; off <<= 1) {
            int add = (tid >= off) ? sh[tid - off] : 0;
            __syncthreads();
            sh[tid] += add;
            __syncthreads();
        }
        if (i < T_SNAP * NBUCK) bbase[i] = carry + sh[tid] - v;
        __syncthreads();
        if (tid == 255) carry += sh[255];
        __syncthreads();
    }
    if (tid < T_SNAP) row_ptr[tid * (N_NODES + 1) + N_NODES] = E_EDGES;
}

// phase 2b: per-bucket row sort -> row_ptr + final colval (writes stay in-region)
__global__ __launch_bounds__(256) void k_p2(const int* __restrict__ bcnt,
        const int* __restrict__ bbase, const uint2* __restrict__ staging,
        const uint4* __restrict__ ovf, const int* __restrict__ ovf_cnt,
        uint2* __restrict__ colval, int* __restrict__ row_ptr) {
    int b = blockIdx.x, t = blockIdx.y, tid = threadIdx.x;
    int idx = t * NBUCK + b;
    int cnt = bcnt[idx];
    int gb  = bbase[idx];                 // base into flat colval [T*E]
    __shared__ int hist[BROWS], cursor[BROWS], sc[BROWS];
    if (tid < BROWS) hist[tid] = 0;
    __syncthreads();
    int staged = min(cnt, BCAP);
    const uint2* st = staging + (size_t)idx * BCAP;
    for (int s = tid; s < staged; s += 256)
        atomicAdd(&hist[st[s].x >> 15], 1);
    int nov = (cnt > staged) ? *ovf_cnt : 0;
    for (int o = tid; o < nov; o += 256) {
        uint4 e = ovf[o];
        if ((int)e.x == idx) atomicAdd(&hist[(e.y >> 15) & 127], 1);
    }
    __syncthreads();
    if (tid < BROWS) sc[tid] = hist[tid];
    __syncthreads();
    for (int off = 1; off < BROWS; off <<= 1) {
        int add = (tid < BROWS && tid >= off) ? sc[tid - off] : 0;
        __syncthreads();
        if (tid < BROWS) sc[tid] += add;
        __syncthreads();
    }
    if (tid < BROWS) {
        int ex = sc[tid] - hist[tid];
        cursor[tid] = ex;
        int row = b * BROWS + tid;
        if (row < N_NODES)
            row_ptr[t * (N_NODES + 1) + row] = gb - t * E_EDGES + ex;
    }
    __syncthreads();
    for (int s = tid; s < staged; s += 256) {
        uint2 e = st[s];
        int rl = e.x >> 15;
        int pos = atomicAdd(&cursor[rl], 1);
        uint2 o2; o2.x = e.x & 0x7FFF; o2.y = e.y;
        colval[(size_t)gb + pos] = o2;
    }
    for (int o = tid; o < nov; o += 256) {
        uint4 e = ovf[o];
        if ((int)e.x == idx) {
            int rl = (e.y >> 15) & 127;
            int pos = atomicAdd(&cursor[rl], 1);
            uint2 o2; o2.x = e.y & 0x7FFF; o2.y = e.z;
            colval[(size_t)gb + pos] = o2;
        }
    }
}

// ---------------------------------------------------------------------------
// Conversions / weight builders
// ---------------------------------------------------------------------------
__global__ void k_cvt(const float* __restrict__ in, u16* __restrict__ out, int n4) {
    int i = blockIdx.x * 256 + threadIdx.x;
    if (i < n4) {
        float4 v = ((const float4*)in)[i];
        ushort4 o;
        o.x = f2b(v.x); o.y = f2b(v.y); o.z = f2b(v.z); o.w = f2b(v.w);
        ((ushort4*)out)[i] = o;
    }
}

__global__ void k_tcvt(const float* __restrict__ in, u16* __restrict__ out, int Kr, int Nc) {
    int i = blockIdx.x * 256 + threadIdx.x;
    if (i < Kr * Nc) {
        int k = i / Nc, n = i - k * Nc;
        out[(size_t)n * Kr + k] = f2b(in[i]);
    }
}

// gate-interleaved [384][128]: col c -> gate g=(c/16)%3, unit jj=(c/48)*16+c%16
__global__ void k_build_g3(const float* __restrict__ W, u16* __restrict__ Bg) {
    int i = blockIdx.x * 256 + threadIdx.x;
    if (i >= 384 * 128) return;
    int c = i >> 7, k = i & 127;
    int g = (c >> 4) % 3;
    int jj = ((c / 48) << 4) + (c & 15);
    Bg[i] = f2b(W[(size_t)(g * 128 + jj) * 128 + k]);
}

__global__ void k_build_bias3(const float* __restrict__ bih, const float* __restrict__ bhh,
                              float* __restrict__ bgi, float* __restrict__ bgh) {
    int c = blockIdx.x * 256 + threadIdx.x;
    if (c >= 384) return;
    int g = (c >> 4) % 3;
    int jj = ((c / 48) << 4) + (c & 15);
    bgi[c] = bih[g * 128 + jj];
    bgh[c] = bhh[g * 128 + jj];
}

// path-B builders (512-col interleave over concat(x,h))
__global__ void k_build_bg(const float* __restrict__ Wih, const float* __restrict__ Whh,
                           u16* __restrict__ Bg) {
    int i = blockIdx.x * 256 + threadIdx.x;
    if (i >= 512 * 256) return;
    int rr = i >> 8, k = i & 255;
    int c = rr >> 4, u = rr & 15, g = c & 3, jj = ((c >> 2) << 4) + u;
    float v;
    if (g == 0)      v = (k < 128) ? Wih[(size_t)jj * 128 + k]         : Whh[(size_t)jj * 128 + k - 128];
    else if (g == 1) v = (k < 128) ? Wih[(size_t)(128 + jj) * 128 + k] : Whh[(size_t)(128 + jj) * 128 + k - 128];
    else if (g == 2) v = (k < 128) ? Wih[(size_t)(256 + jj) * 128 + k] : 0.f;
    else             v = (k < 128) ? 0.f : Whh[(size_t)(256 + jj) * 128 + k - 128];
    Bg[i] = f2b(v);
}

__global__ void k_build_bgb(const float* __restrict__ bih, const float* __restrict__ bhh,
                            float* __restrict__ bgb) {
    int rr = blockIdx.x * 256 + threadIdx.x;
    if (rr >= 512) return;
    int c = rr >> 4, u = rr & 15, g = c & 3, jj = ((c >> 2) << 4) + u;
    float v;
    if (g == 0)      v = bih[jj] + bhh[jj];
    else if (g == 1) v = bih[128 + jj] + bhh[128 + jj];
    else if (g == 2) v = bih[256 + jj];
    else             v = bhh[256 + jj];
    bgb[rr] = v;
}

// ---------------------------------------------------------------------------
// Batched SpMM
// ---------------------------------------------------------------------------
template<int D, bool RELU>
__global__ void k_spmm_all(const int* __restrict__ row_ptr_all, const uint2* __restrict__ colval_all,
                           int t0, const u16* __restrict__ X, size_t xtstride,
                           const float* __restrict__ bias, u16* __restrict__ Out) {
    constexpr int V = D / 64;
    int row = blockIdx.x, tl = blockIdx.y, t = t0 + tl, j = threadIdx.x;
    const int*   rp = row_ptr_all + (size_t)t * (N_NODES + 1);
    const uint2* cv = colval_all + (size_t)t * E_EDGES;
    const u16*   Xt = X + xtstride * tl;
    float acc[V];
    #pragma unroll
    for (int i = 0; i < V; ++i) acc[i] = bias[j * V + i];
    int s = rp[row], e = rp[row + 1];
    for (int k = s; k < e; ++k) {
        uint2 a = cv[k];
        float va = __uint_as_float(a.y);
        const u16* xr = Xt + (size_t)a.x * D + j * V;
        if constexpr (V == 4) {
            ushort4 x = *(const ushort4*)xr;
            acc[0] = fmaf(va, b2f(x.x), acc[0]);
            acc[1] = fmaf(va, b2f(x.y), acc[1]);
            acc[2] = fmaf(va, b2f(x.z), acc[2]);
            acc[3] = fmaf(va, b2f(x.w), acc[3]);
        } else {
            ushort2 x = *(const ushort2*)xr;
            acc[0] = fmaf(va, b2f(x.x), acc[0]);
            acc[1] = fmaf(va, b2f(x.y), acc[1]);
        }
    }
    u16* o = Out + ((size_t)tl * N_NODES + row) * D + j * V;
    if constexpr (V == 4) {
        ushort4 ov;
        ov.x = f2b(RELU ? fmaxf(acc[0], 0.f) : acc[0]);
        ov.y = f2b(RELU ? fmaxf(acc[1], 0.f) : acc[1]);
        ov.z = f2b(RELU ? fmaxf(acc[2], 0.f) : acc[2]);
        ov.w = f2b(RELU ? fmaxf(acc[3], 0.f) : acc[3]);
        *(ushort4*)o = ov;
    } else {
        ushort2 ov;
        ov.x = f2b(RELU ? fmaxf(acc[0], 0.f) : acc[0]);
        ov.y = f2b(RELU ? fmaxf(acc[1], 0.f) : acc[1]);
        *(ushort2*)o = ov;
    }
}

// ---------------------------------------------------------------------------
// bf16 MFMA GEMM: C[M,Nc] = A[M,K] @ B^T (+bias), out bf16. tile 64x128.
// ---------------------------------------------------------------------------
template<int KC, bool BIAS>
__global__ __launch_bounds__(256) void k_mgemm(
        const u16* __restrict__ A, const u16* __restrict__ B, int ldb,
        const float* __restrict__ bias, u16* __restrict__ C, int ldc, int M) {
    constexpr int K = KC * 32;
    __shared__ bf16x8 frag[8 * KC * 64];
    int tid = threadIdx.x, lane = tid & 63, wave = tid >> 6;
    int m0 = blockIdx.y * 64, n0 = blockIdx.x * 128;

    for (int f = wave; f < 8 * KC; f += 4) {
        int nl = f / KC, kc = f % KC;
        frag[f * 64 + lane] = *(const bf16x8*)(B + (size_t)(n0 + nl * 16 + (lane & 15)) * ldb
                                               + kc * 32 + ((lane >> 4) << 3));
    }
    __syncthreads();

    int arow = m0 + wave * 16 + (lane & 15);
    bool rowok = arow < M;
    const u16* ap = A + (size_t)arow * K + ((lane >> 4) << 3);
    bf16x8 zf = {0, 0, 0, 0, 0, 0, 0, 0};
    bf16x8 af[KC];
    #pragma unroll
    for (int kc = 0; kc < KC; ++kc)
        af[kc] = rowok ? *(const bf16x8*)(ap + kc * 32) : zf;

    f32x4 acc[8] = {};
    #pragma unroll
    for (int kc = 0; kc < KC; ++kc)
        #pragma unroll
        for (int nl = 0; nl < 8; ++nl)
            acc[nl] = __builtin_amdgcn_mfma_f32_16x16x32_bf16(
                af[kc], frag[(nl * KC + kc) * 64 + lane], acc[nl], 0, 0, 0);

    int r0 = m0 + wave * 16 + ((lane >> 4) << 2);
    #pragma unroll
    for (int nl = 0; nl < 8; ++nl) {
        int col = n0 + nl * 16 + (lane & 15);
        float bv = BIAS ? bias[col] : 0.f;
        #pragma unroll
        for (int r = 0; r < 4; ++r) {
            int row = r0 + r;
            if (row < M) C[(size_t)row * ldc + col] = f2b(acc[nl][r] + bv);
        }
    }
}

// ---------------------------------------------------------------------------
// Path A sequential GRU step: gh = h @ Bg_h^T (K=128, N=384 interleaved),
// epilogue reads precomputed GI (bf16, incl. b_ih) and does GRU pointwise.
// tile 64 x 192, grid (2, 313).
// ---------------------------------------------------------------------------
__global__ __launch_bounds__(256) void k_gru2(
        const u16* __restrict__ HbfIn, const u16* __restrict__ Bg_h,
        const float* __restrict__ bgh, const u16* __restrict__ GI_t,
        float* __restrict__ H, u16* __restrict__ HbfOut) {
    __shared__ bf16x8 frag[48 * 64];
    int tid = threadIdx.x, lane = tid & 63, wave = tid >> 6;
    int m0 = blockIdx.y * 64, n0 = blockIdx.x * 192;

    for (int f = wave; f < 48; f += 4) {
        int nl = f >> 2, kc = f & 3;
        frag[f * 64 + lane] = *(const bf16x8*)(Bg_h + (size_t)(n0 + nl * 16 + (lane & 15)) * 128
                                               + kc * 32 + ((lane >> 4) << 3));
    }
    __syncthreads();

    int arow = m0 + wave * 16 + (lane & 15);
    bool rowok = arow < N_NODES;
    bf16x8 zf = {0, 0, 0, 0, 0, 0, 0, 0};
    const u16* ap = HbfIn + (size_t)arow * 128 + ((lane >> 4) << 3);
    bf16x8 af[4];
    #pragma unroll
    for (int kc = 0; kc < 4; ++kc)
        af[kc] = rowok ? *(const bf16x8*)(ap + kc * 32) : zf;

    f32x4 acc[12] = {};
    #pragma unroll
    for (int kc = 0; kc < 4; ++kc)
        #pragma unroll
        for (int nl = 0; nl < 12; ++nl)
            acc[nl] = __builtin_amdgcn_mfma_f32_16x16x32_bf16(
                af[kc], frag[(nl * 4 + kc) * 64 + lane], acc[nl], 0, 0, 0);

    int r0 = m0 + wave * 16 + ((lane >> 4) << 2);
    int u = lane & 15;
    #pragma unroll
    for (int ub = 0; ub < 4; ++ub) {
        int cb = n0 + ub * 48;
        float br = bgh[cb + u], bz = bgh[cb + 16 + u], bn = bgh[cb + 32 + u];
        int jj = ((n0 / 48 + ub) << 4) + u;
        #pragma unroll
        for (int rr = 0; rr < 4; ++rr) {
            int row = r0 + rr;
            if (row >= N_NODES) continue;
            const u16* gi = GI_t + (size_t)row * 384 + cb;
            float gr = b2f(gi[u]), gz = b2f(gi[16 + u]), gn = b2f(gi[32 + u]);
            float rg = 1.f / (1.f + expf(-(gr + acc[ub * 3 + 0][rr] + br)));
            float zg = 1.f / (1.f + expf(-(gz + acc[ub * 3 + 1][rr] + bz)));
            float ng = tanhf(gn + rg * (acc[ub * 3 + 2][rr] + bn));
            size_t hidx = (size_t)row * HDIM + jj;
            float ho = H[hidx];
            float hn = (1.f - zg) * ng + zg * ho;
            H[hidx] = hn;
            HbfOut[hidx] = f2b(hn);
        }
    }
}

// ---------------------------------------------------------------------------
// Path B fused GRU step (K=256 over [X2_t | h]), 512-col interleave
// ---------------------------------------------------------------------------
__global__ __launch_bounds__(256) void k_gru_gemm(
        const u16* __restrict__ X2t, const u16* __restrict__ HbfIn,
        const u16* __restrict__ Bg, const float* __restrict__ bgb,
        float* __restrict__ H, u16* __restrict__ HbfOut) {
    __shared__ bf16x8 frag[64 * 64];
    int tid = threadIdx.x, lane = tid & 63, wave = tid >> 6;
    int m0 = blockIdx.y * 64, n0 = blockIdx.x * 128;

    for (int f = wave; f < 64; f += 4) {
        int nl = f >> 3, kc = f & 7;
        frag[f * 64 + lane] = *(const bf16x8*)(Bg + (size_t)(n0 + nl * 16 + (lane & 15)) * 256
                                               + kc * 32 + ((lane >> 4) << 3));
    }
    __syncthreads();

    int arow = m0 + wave * 16 + (lane & 15);
    bool rowok = arow < N_NODES;
    bf16x8 zf = {0, 0, 0, 0, 0, 0, 0, 0};
    const u16* a1 = X2t   + (size_t)arow * 128 + ((lane >> 4) << 3);
    const u16* a2 = HbfIn + (size_t)arow * 128 + ((lane >> 4) << 3);
    bf16x8 af[8];
    #pragma unroll
    for (int kc = 0; kc < 4; ++kc) af[kc]     = rowok ? *(const bf16x8*)(a1 + kc * 32) : zf;
    #pragma unroll
    for (int kc = 0; kc < 4; ++kc) af[4 + kc] = rowok ? *(const bf16x8*)(a2 + kc * 32) : zf;

    f32x4 acc[8] = {};
    #pragma unroll
    for (int kc = 0; kc < 8; ++kc)
        #pragma unroll
        for (int nl = 0; nl < 8; ++nl)
            acc[nl] = __builtin_amdgcn_mfma_f32_16x16x32_bf16(
                af[kc], frag[(nl * 8 + kc) * 64 + lane], acc[nl], 0, 0, 0);

    int rbase = m0 + wave * 16 + ((lane >> 4) << 2);
    #pragma unroll
    for (int hb = 0; hb < 2; ++hb) {
        int jj = (2 * blockIdx.x + hb) * 16 + (lane & 15);
        float br = bgb[n0 + (4 * hb + 0) * 16 + (lane & 15)];
        float bz = bgb[n0 + (4 * hb + 1) * 16 + (lane & 15)];
        float bi = bgb[n0 + (4 * hb + 2) * 16 + (lane & 15)];
        float bh = bgb[n0 + (4 * hb + 3) * 16 + (lane & 15)];
        #pragma unroll
        for (int r = 0; r < 4; ++r) {
            int row = rbase + r;
            if (row >= N_NODES) continue;
            float rg = acc[4 * hb + 0][r] + br;
            float zg = acc[4 * hb + 1][r] + bz;
            float ig = acc[4 * hb + 2][r] + bi;
            float hg = acc[4 * hb + 3][r] + bh;
            rg = 1.f / (1.f + expf(-rg));
            zg = 1.f / (1.f + expf(-zg));
            float ng = tanhf(ig + rg * hg);
            size_t idx = (size_t)row * HDIM + jj;
            float ho = H[idx];
            float hn = (1.f - zg) * ng + zg * ho;
            H[idx] = hn;
            HbfOut[idx] = f2b(hn);
        }
    }
}

// ---------------------------------------------------------------------------
// BatchNorm
// ---------------------------------------------------------------------------
__global__ void k_bnstats(const float* __restrict__ h, float* __restrict__ stats) {
    int j = threadIdx.x;
    int r0 = blockIdx.x * 200;
    float s = 0.f, sq = 0.f;
    for (int r = r0; r < r0 + 200; ++r) {
        float v = h[(size_t)r * HDIM + j];
        s += v; sq += v * v;
    }
    atomicAdd(&stats[j], s);
    atomicAdd(&stats[128 + j], sq);
}

__global__ void k_bnapply(const float* __restrict__ h, const float* __restrict__ stats,
                          const float* __restrict__ gamma, const float* __restrict__ beta,
                          u16* __restrict__ emb) {
    int i = blockIdx.x * 256 + threadIdx.x;
    if (i >= N_NODES * HDIM) return;
    int j = i & 127;
    float mean = stats[j] * (1.f / N_NODES);
    float var  = stats[128 + j] * (1.f / N_NODES) - mean * mean;
    emb[i] = f2b((h[i] - mean) * rsqrtf(var + BN_EPS) * gamma[j] + beta[j]);
}

// ---------------------------------------------------------------------------
// Edge predictor
// ---------------------------------------------------------------------------
__global__ __launch_bounds__(256) void k_edge(const int* __restrict__ edges,
        const u16* __restrict__ P, const u16* __restrict__ Q,
        const float* __restrict__ We2, const float* __restrict__ be2,
        float* __restrict__ out) {
    int e = blockIdx.x * 4 + (threadIdx.x >> 6);
    int lane = threadIdx.x & 63;
    if (e >= EP_EDGES) return;
    int u = edges[e];
    int v = edges[EP_EDGES + e];
    ushort4 pv = *(const ushort4*)(P + (size_t)u * NHID_E + lane * 4);
    ushort4 qv = *(const ushort4*)(Q + (size_t)v * NHID_E + lane * 4);
    const float4* w = (const float4*)(We2 + lane * 8);
    float4 w0 = w[0], w1 = w[1];
    float h0 = fmaxf(b2f(pv.x) + b2f(qv.x), 0.f);
    float h1 = fmaxf(b2f(pv.y) + b2f(qv.y), 0.f);
    float h2 = fmaxf(b2f(pv.z) + b2f(qv.z), 0.f);
    float h3 = fmaxf(b2f(pv.w) + b2f(qv.w), 0.f);
    float l0 = h0 * w0.x + h1 * w0.z + h2 * w1.x + h3 * w1.z;
    float l1 = h0 * w0.y + h1 * w0.w + h2 * w1.y + h3 * w1.w;
    #pragma unroll
    for (int off = 32; off > 0; off >>= 1) {
        l0 += __shfl_down(l0, off);
        l1 += __shfl_down(l1, off);
    }
    if (lane == 0) {
        l0 += be2[0]; l1 += be2[1];
        float m = fmaxf(l0, l1);
        float lse = m + logf(expf(l0 - m) + expf(l1 - m));
        out[(size_t)e * 2 + 0] = l0 - lse;
        out[(size_t)e * 2 + 1] = l1 - lse;
    }
}

// ---------------------------------------------------------------------------
extern "C" void kernel_launch(void* const* d_in, const int* in_sizes, int n_in,
                              void* d_out, int out_size, void* d_ws, size_t ws_size,
                              hipStream_t stream) {
    const int*   adj_rows = (const int*)  d_in[0];
    const int*   adj_cols = (const int*)  d_in[1];
    const float* adj_vals = (const float*)d_in[2];
    const int*   edges    = (const int*)  d_in[3];
    const float* W0   = (const float*)d_in[4];
    const float* b0   = (const float*)d_in[5];
    const float* W1   = (const float*)d_in[6];
    const float* b1   = (const float*)d_in[7];
    const float* W_ih = (const float*)d_in[8];
    const float* W_hh = (const float*)d_in[9];
    const float* b_ih = (const float*)d_in[10];
    const float* b_hh = (const float*)d_in[11];
    const float* gamma = (const float*)d_in[12];
    const float* beta  = (const float*)d_in[13];
    const float* We1  = (const float*)d_in[14];
    const float* be1  = (const float*)d_in[15];
    const float* We2  = (const float*)d_in[16];
    const float* be2  = (const float*)d_in[17];
    float* out = (float*)d_out;

    char* ws = (char*)d_ws;
    size_t off = 0;
    auto alloc = [&](size_t bytes) -> void* {
        void* p = ws + off;
        off += (bytes + 255) & ~(size_t)255;
        return p;
    };
    // ---- persistent ----
    int*   row_ptr = (int*)  alloc((size_t)T_SNAP * (N_NODES + 1) * 4);
    uint2* colval  = (uint2*)alloc((size_t)T_SNAP * E_EDGES * 8);
    u16*   W0_bf   = (u16*)  alloc((size_t)N_NODES * NHID * 2);
    u16*   W1t     = (u16*)  alloc((size_t)NOUT * NHID * 2);
    u16*   We1T    = (u16*)  alloc((size_t)NHID_E * 256 * 2);
    u16*   Bg_i    = (u16*)  alloc((size_t)384 * 128 * 2);
    u16*   Bg_h    = (u16*)  alloc((size_t)384 * 128 * 2);
    float* bgi     = (float*)alloc(384 * 4);
    float* bgh     = (float*)alloc(384 * 4);
    u16*   BgB     = (u16*)  alloc((size_t)512 * 256 * 2);
    float* bgbB    = (float*)alloc(512 * 4);
    float* h       = (float*)alloc((size_t)N_NODES * HDIM * 4);
    u16*   h_bfA   = (u16*)  alloc((size_t)N_NODES * HDIM * 2);
    u16*   h_bfB   = (u16*)  alloc((size_t)N_NODES * HDIM * 2);
    float* stats   = (float*)alloc(256 * 4);
    int*   bcnt    = (int*)  alloc((size_t)T_SNAP * NBUCK * 4);
    int*   bbase   = (int*)  alloc((size_t)T_SNAP * NBUCK * 4);
    int*   ovf_cnt = (int*)  alloc(256);
    size_t mark = off;

    // ---- union region: CSR phase ----
    off = mark;
    uint2* staging = (uint2*)alloc((size_t)T_SNAP * NBUCK * BCAP * 8);
    uint4* ovf     = (uint4*)alloc((size_t)T_SNAP * E_EDGES * 16);
    size_t csr_end = off;

    // ---- union region: compute phase ----
    const int BT = 4;
    off = mark;
    u16* X0_b = (u16*)alloc((size_t)BT * N_NODES * NHID * 2);
    u16* Y_b  = (u16*)alloc((size_t)BT * N_NODES * NOUT * 2);
    u16* X2_b = (u16*)alloc((size_t)BT * N_NODES * NOUT * 2);   // path A group buf
    u16* X2_all = (u16*)(ws + off);                              // path B alias (after X0/Y)
    size_t pathB_end = off + (((size_t)T_SNAP * N_NODES * NOUT * 2 + 255) & ~(size_t)255);
    u16* GI_all = (u16*)alloc((size_t)T_SNAP * N_NODES * 384 * 2);  // path A
    size_t pathA_end = off;

    // ---- union region: post phase ----
    off = mark;
    u16* emb = (u16*)alloc((size_t)N_NODES * HDIM * 2);
    u16* P   = (u16*)alloc((size_t)N_NODES * NHID_E * 2);
    u16* Q   = (u16*)alloc((size_t)N_NODES * NHID_E * 2);
    size_t post_end = off;

    bool pathA = (pathA_end + (16 << 20) <= ws_size);
    size_t need = csr_end;
    if (pathB_end > need) need = pathB_end;
    if (post_end  > need) need = post_end;
    if (pathA && pathA_end > need) need = pathA_end;
    if (need > ws_size) return;   // visible failure instead of corruption

    hipMemsetAsync(bcnt,    0, (size_t)T_SNAP * NBUCK * 4, stream);
    hipMemsetAsync(ovf_cnt, 0, 256, stream);
    hipMemsetAsync(stats,   0, 256 * 4, stream);
    hipMemsetAsync(h,       0, (size_t)N_NODES * HDIM * 4, stream);
    hipMemsetAsync(h_bfA,   0, (size_t)N_NODES * HDIM * 2, stream);

    // ---- CSR build v2 ----
    dim3 p1g((E_EDGES + 4095) / 4096, T_SNAP);
    k_p1   <<<p1g, 256, 0, stream>>>(adj_rows, adj_cols, adj_vals, bcnt, staging, ovf, ovf_cnt);
    k_bscan<<<1, 256, 0, stream>>>(bcnt, bbase, row_ptr);
    k_p2   <<<dim3(NBUCK, T_SNAP), 256, 0, stream>>>(bcnt, bbase, staging, ovf, ovf_cnt,
                                                     colval, row_ptr);

    // ---- weight conversions ----
    k_cvt       <<<(N_NODES * NHID / 4 + 255) / 256, 256, 0, stream>>>(W0, W0_bf, N_NODES * NHID / 4);
    k_tcvt      <<<(NHID * NOUT + 255) / 256,  256, 0, stream>>>(W1, W1t, NHID, NOUT);
    k_tcvt      <<<(256 * NHID_E + 255) / 256, 256, 0, stream>>>(We1, We1T, 256, NHID_E);
    if (pathA) {
        k_build_g3   <<<(384 * 128 + 255) / 256, 256, 0, stream>>>(W_ih, Bg_i);
        k_build_g3   <<<(384 * 128 + 255) / 256, 256, 0, stream>>>(W_hh, Bg_h);
        k_build_bias3<<<2, 256, 0, stream>>>(b_ih, b_hh, bgi, bgh);
    } else {
        k_build_bg <<<(512 * 256 + 255) / 256, 256, 0, stream>>>(W_ih, W_hh, BgB);
        k_build_bgb<<<2, 256, 0, stream>>>(b_ih, b_hh, bgbB);
    }

    // ---- batched GCN (+ GI precompute on path A) ----
    for (int g = 0; g < T_SNAP; g += BT) {
        k_spmm_all<NHID, true><<<dim3(N_NODES, BT), 64, 0, stream>>>(
            row_ptr, colval, g, W0_bf, 0, b0, X0_b);
        int M = BT * N_NODES;
        k_mgemm<8, false><<<dim3(1, (M + 63) / 64), 256, 0, stream>>>(
            X0_b, W1t, NHID, nullptr, Y_b, NOUT, M);
        u16* x2dst = pathA ? X2_b : (X2_all + (size_t)g * N_NODES * NOUT);
        k_spmm_all<NOUT, false><<<dim3(N_NODES, BT), 64, 0, stream>>>(
            row_ptr, colval, g, Y_b, (size_t)N_NODES * NOUT, b1, x2dst);
        if (pathA)
            k_mgemm<4, true><<<dim3(3, (M + 63) / 64), 256, 0, stream>>>(
                X2_b, Bg_i, 128, bgi, GI_all + (size_t)g * N_NODES * 384, 384, M);
    }

    // ---- GRU over time ----
    for (int t = 0; t < T_SNAP; ++t) {
        const u16* hin  = (t & 1) ? h_bfB : h_bfA;
        u16*       hout = (t & 1) ? h_bfA : h_bfB;
        if (pathA)
            k_gru2<<<dim3(2, (N_NODES + 63) / 64), 256, 0, stream>>>(
                hin, Bg_h, bgh, GI_all + (size_t)t * N_NODES * 384, h, hout);
        else
            k_gru_gemm<<<dim3(4, (N_NODES + 63) / 64), 256, 0, stream>>>(
                X2_all + (size_t)t * N_NODES * NOUT, hin, BgB, bgbB, h, hout);
    }

    // ---- BatchNorm ----
    k_bnstats<<<100, 128, 0, stream>>>(h, stats);
    k_bnapply<<<(N_NODES * HDIM + 255) / 256, 256, 0, stream>>>(h, stats, gamma, beta, emb);

    // ---- Edge MLP precompute + predictor ----
    k_mgemm<4, true><<<dim3(2, (N_NODES + 63) / 64), 256, 0, stream>>>(
        emb, We1T, 256, be1, P, NHID_E, N_NODES);
    k_mgemm<4, false><<<dim3(2, (N_NODES + 63) / 64), 256, 0, stream>>>(
        emb, We1T + 128, 256, nullptr, Q, NHID_E, N_NODES);
    k_edge<<<(EP_EDGES + 3) / 4, 256, 0, stream>>>(edges, P, Q, We2, be2, out);
}

// Round 4
// 1387.953 us; speedup vs baseline: 2.9571x; 1.0520x over previous
//
#include <hip/hip_runtime.h>
#include <math.h>

#define N_NODES 20000
#define NHID    256
#define NOUT    128
#define HDIM    128
#define NHID_E  256
#define T_SNAP  16
#define E_EDGES 320000
#define EP_EDGES 100000
#define BN_EPS  1e-5f

#define BROWS 128                    // rows per bucket
#define NBUCK 157                    // ceil(N_NODES / BROWS)
#define BCAP  4096                   // staging capacity per bucket

typedef unsigned short u16;
typedef __attribute__((ext_vector_type(8))) short bf16x8;
typedef __attribute__((ext_vector_type(8))) unsigned short u16x8;
typedef __attribute__((ext_vector_type(4))) float f32x4;

__device__ __forceinline__ u16 f2b(float f) {
    unsigned u = __float_as_uint(f);
    u += 0x7FFFu + ((u >> 16) & 1u);
    return (u16)(u >> 16);
}
__device__ __forceinline__ float b2f(u16 s) { return __uint_as_float(((unsigned)s) << 16); }

// ---------------------------------------------------------------------------
// CSR build v2, phase 1: block-local counting sort by bucket, append runs.
// Entry packing: x = col | ((row&127)<<15)  (col < 2^15), y = val bits.
// ---------------------------------------------------------------------------
__global__ __launch_bounds__(256) void k_p1(const int* __restrict__ rows,
        const int* __restrict__ cols, const float* __restrict__ vals,
        int* __restrict__ bcnt, uint2* __restrict__ staging,
        uint4* __restrict__ ovf, int* __restrict__ ovf_cnt) {
    int t = blockIdx.y;
    int base = blockIdx.x * 4096;
    int tid = threadIdx.x;
    __shared__ int hist[256], sc[256], excl[256], cursor[256], gbase[256];
    __shared__ uint2 ebuf[4096];
    __shared__ u16 ebuck[4096];
    hist[tid] = 0;
    __syncthreads();
    const int*   rt = rows + (size_t)t * E_EDGES;
    const int*   ct = cols + (size_t)t * E_EDGES;
    const float* vt = vals + (size_t)t * E_EDGES;
    #pragma unroll
    for (int k = 0; k < 16; ++k) {
        int i = base + k * 256 + tid;
        if (i < E_EDGES) atomicAdd(&hist[rt[i] >> 7], 1);
    }
    __syncthreads();
    sc[tid] = hist[tid];
    __syncthreads();
    for (int off = 1; off < 256; off <<= 1) {
        int add = (tid >= off) ? sc[tid - off] : 0;
        __syncthreads();
        sc[tid] += add;
        __syncthreads();
    }
    excl[tid]   = sc[tid] - hist[tid];
    cursor[tid] = sc[tid] - hist[tid];
    __syncthreads();
    #pragma unroll
    for (int k = 0; k < 16; ++k) {
        int i = base + k * 256 + tid;
        if (i < E_EDGES) {
            int r = rt[i];
            int b = r >> 7;
            int s = atomicAdd(&cursor[b], 1);
            uint2 e;
            e.x = (unsigned)ct[i] | ((unsigned)(r & 127) << 15);
            e.y = __float_as_uint(vt[i]);
            ebuf[s]  = e;
            ebuck[s] = (u16)b;
        }
    }
    __syncthreads();
    if (hist[tid] > 0) gbase[tid] = atomicAdd(&bcnt[t * NBUCK + tid], hist[tid]);
    __syncthreads();
    int nvalid = min(4096, E_EDGES - base);
    for (int s = tid; s < nvalid; s += 256) {
        int b = ebuck[s];
        int g = gbase[b] + (s - excl[b]);
        if (g < BCAP) {
            staging[((size_t)t * NBUCK + b) * BCAP + g] = ebuf[s];
        } else {
            int o = atomicAdd(ovf_cnt, 1);
            uint4 e4; e4.x = (unsigned)(t * NBUCK + b); e4.y = ebuf[s].x; e4.z = ebuf[s].y; e4.w = 0;
            ovf[o] = e4;
        }
    }
}

// phase 2a: exclusive scan of all bucket counts (2512 values), one block
__global__ void k_bscan(const int* __restrict__ bcnt, int* __restrict__ bbase,
                        int* __restrict__ row_ptr) {
    __shared__ int sh[256];
    __shared__ int carry;
    int tid = threadIdx.x;
    if (tid == 0) carry = 0;
    __syncthreads();
    for (int b0 = 0; b0 < T_SNAP * NBUCK; b0 += 256) {
        int i = b0 + tid;
        int v = (i < T_SNAP * NBUCK) ? bcnt[i] : 0;
        sh[tid] = v;
        __syncthreads();
        for (int off = 1; off < 256; off <<= 1) {
            int add = (tid >= off) ? sh[tid - off] : 0;
            __syncthreads();
            sh[tid] += add;
            __syncthreads();
        }
        if (i < T_SNAP * NBUCK) bbase[i] = carry + sh[tid] - v;
        __syncthreads();
        if (tid == 255) carry += sh[255];
        __syncthreads();
    }
    if (tid < T_SNAP) row_ptr[tid * (N_NODES + 1) + N_NODES] = E_EDGES;
}

// phase 2b: per-bucket row sort -> row_ptr + final colval (writes stay in-region)
__global__ __launch_bounds__(256) void k_p2(const int* __restrict__ bcnt,
        const int* __restrict__ bbase, const uint2* __restrict__ staging,
        const uint4* __restrict__ ovf, const int* __restrict__ ovf_cnt,
        uint2* __restrict__ colval, int* __restrict__ row_ptr) {
    int b = blockIdx.x, t = blockIdx.y, tid = threadIdx.x;
    int idx = t * NBUCK + b;
    int cnt = bcnt[idx];
    int gb  = bbase[idx];                 // base into flat colval [T*E]
    __shared__ int hist[BROWS], cursor[BROWS], sc[BROWS];
    if (tid < BROWS) hist[tid] = 0;
    __syncthreads();
    int staged = min(cnt, BCAP);
    const uint2* st = staging + (size_t)idx * BCAP;
    for (int s = tid; s < staged; s += 256)
        atomicAdd(&hist[st[s].x >> 15], 1);
    int nov = (cnt > staged) ? *ovf_cnt : 0;
    for (int o = tid; o < nov; o += 256) {
        uint4 e = ovf[o];
        if ((int)e.x == idx) atomicAdd(&hist[(e.y >> 15) & 127], 1);
    }
    __syncthreads();
    if (tid < BROWS) sc[tid] = hist[tid];
    __syncthreads();
    for (int off = 1; off < BROWS; off <<= 1) {
        int add = (tid < BROWS && tid >= off) ? sc[tid - off] : 0;
        __syncthreads();
        if (tid < BROWS) sc[tid] += add;
        __syncthreads();
    }
    if (tid < BROWS) {
        int ex = sc[tid] - hist[tid];
        cursor[tid] = ex;
        int row = b * BROWS + tid;
        if (row < N_NODES)
            row_ptr[t * (N_NODES + 1) + row] = gb - t * E_EDGES + ex;
    }
    __syncthreads();
    for (int s = tid; s < staged; s += 256) {
        uint2 e = st[s];
        int rl = e.x >> 15;
        int pos = atomicAdd(&cursor[rl], 1);
        uint2 o2; o2.x = e.x & 0x7FFF; o2.y = e.y;
        colval[(size_t)gb + pos] = o2;
    }
    for (int o = tid; o < nov; o += 256) {
        uint4 e = ovf[o];
        if ((int)e.x == idx) {
            int rl = (e.y >> 15) & 127;
            int pos = atomicAdd(&cursor[rl], 1);
            uint2 o2; o2.x = e.y & 0x7FFF; o2.y = e.z;
            colval[(size_t)gb + pos] = o2;
        }
    }
}

// ---------------------------------------------------------------------------
// Conversions / weight builders
// ---------------------------------------------------------------------------
__global__ void k_cvt(const float* __restrict__ in, u16* __restrict__ out, int n4) {
    int i = blockIdx.x * 256 + threadIdx.x;
    if (i < n4) {
        float4 v = ((const float4*)in)[i];
        ushort4 o;
        o.x = f2b(v.x); o.y = f2b(v.y); o.z = f2b(v.z); o.w = f2b(v.w);
        ((ushort4*)out)[i] = o;
    }
}

__global__ void k_tcvt(const float* __restrict__ in, u16* __restrict__ out, int Kr, int Nc) {
    int i = blockIdx.x * 256 + threadIdx.x;
    if (i < Kr * Nc) {
        int k = i / Nc, n = i - k * Nc;
        out[(size_t)n * Kr + k] = f2b(in[i]);
    }
}

// gate-interleaved [384][128]: col c -> gate g=(c/16)%3, unit jj=(c/48)*16+c%16
__global__ void k_build_g3(const float* __restrict__ W, u16* __restrict__ Bg) {
    int i = blockIdx.x * 256 + threadIdx.x;
    if (i >= 384 * 128) return;
    int c = i >> 7, k = i & 127;
    int g = (c >> 4) % 3;
    int jj = ((c / 48) << 4) + (c & 15);
    Bg[i] = f2b(W[(size_t)(g * 128 + jj) * 128 + k]);
}

__global__ void k_build_bias3(const float* __restrict__ bih, const float* __restrict__ bhh,
                              float* __restrict__ bgi, float* __restrict__ bgh) {
    int c = blockIdx.x * 256 + threadIdx.x;
    if (c >= 384) return;
    int g = (c >> 4) % 3;
    int jj = ((c / 48) << 4) + (c & 15);
    bgi[c] = bih[g * 128 + jj];
    bgh[c] = bhh[g * 128 + jj];
}

// path-B builders (512-col interleave over concat(x,h))
__global__ void k_build_bg(const float* __restrict__ Wih, const float* __restrict__ Whh,
                           u16* __restrict__ Bg) {
    int i = blockIdx.x * 256 + threadIdx.x;
    if (i >= 512 * 256) return;
    int rr = i >> 8, k = i & 255;
    int c = rr >> 4, u = rr & 15, g = c & 3, jj = ((c >> 2) << 4) + u;
    float v;
    if (g == 0)      v = (k < 128) ? Wih[(size_t)jj * 128 + k]         : Whh[(size_t)jj * 128 + k - 128];
    else if (g == 1) v = (k < 128) ? Wih[(size_t)(128 + jj) * 128 + k] : Whh[(size_t)(128 + jj) * 128 + k - 128];
    else if (g == 2) v = (k < 128) ? Wih[(size_t)(256 + jj) * 128 + k] : 0.f;
    else             v = (k < 128) ? 0.f : Whh[(size_t)(256 + jj) * 128 + k - 128];
    Bg[i] = f2b(v);
}

__global__ void k_build_bgb(const float* __restrict__ bih, const float* __restrict__ bhh,
                            float* __restrict__ bgb) {
    int rr = blockIdx.x * 256 + threadIdx.x;
    if (rr >= 512) return;
    int c = rr >> 4, u = rr & 15, g = c & 3, jj = ((c >> 2) << 4) + u;
    float v;
    if (g == 0)      v = bih[jj] + bhh[jj];
    else if (g == 1) v = bih[128 + jj] + bhh[128 + jj];
    else if (g == 2) v = bih[256 + jj];
    else             v = bhh[256 + jj];
    bgb[rr] = v;
}

// ---------------------------------------------------------------------------
// SpMM layer0 (D=256, shared X table): block = 4 waves = 4 rows.
// Each wave: 2 half-waves process 2 edges/iter, 16B/lane gather (32x16B=512B row).
// ---------------------------------------------------------------------------
template<bool RELU>
__global__ __launch_bounds__(256) void k_spmm0(
        const int* __restrict__ rp_all, const uint2* __restrict__ cv_all,
        int t0, const u16* __restrict__ X,
        const float* __restrict__ bias, u16* __restrict__ Out) {
    int lane = threadIdx.x & 63;
    int row = blockIdx.x * 4 + (threadIdx.x >> 6);
    int tl = blockIdx.y, t = t0 + tl;
    const int*   rp = rp_all + (size_t)t * (N_NODES + 1);
    const uint2* cv = cv_all + (size_t)t * E_EDGES;
    int hw = lane >> 5, l = lane & 31;
    float acc[8] = {};
    int s = rp[row], e = rp[row + 1];
    for (int k = s + hw; k < e; k += 2) {
        uint2 a = cv[k];
        float va = __uint_as_float(a.y);
        u16x8 x = *(const u16x8*)(X + (size_t)a.x * NHID + l * 8);
        #pragma unroll
        for (int i = 0; i < 8; ++i)
            acc[i] = fmaf(va, b2f(x[i]), acc[i]);
    }
    #pragma unroll
    for (int i = 0; i < 8; ++i) {
        float v = acc[i] + __shfl_xor(acc[i], 32);
        v += bias[l * 8 + i];
        acc[i] = RELU ? fmaxf(v, 0.f) : v;
    }
    if (hw == 0) {
        u16x8 o;
        #pragma unroll
        for (int i = 0; i < 8; ++i) o[i] = f2b(acc[i]);
        *(u16x8*)(Out + ((size_t)tl * N_NODES + row) * NHID + l * 8) = o;
    }
}

// ---------------------------------------------------------------------------
// SpMM layer1 (D=128, per-snapshot X): 4 quarter-waves, 4 edges/iter, 16B/lane.
// ---------------------------------------------------------------------------
template<bool RELU>
__global__ __launch_bounds__(256) void k_spmm1(
        const int* __restrict__ rp_all, const uint2* __restrict__ cv_all,
        int t0, const u16* __restrict__ X, size_t xtstride,
        const float* __restrict__ bias, u16* __restrict__ Out) {
    int lane = threadIdx.x & 63;
    int row = blockIdx.x * 4 + (threadIdx.x >> 6);
    int tl = blockIdx.y, t = t0 + tl;
    const int*   rp = rp_all + (size_t)t * (N_NODES + 1);
    const uint2* cv = cv_all + (size_t)t * E_EDGES;
    const u16*   Xt = X + xtstride * tl;
    int qw = lane >> 4, l = lane & 15;
    float acc[8] = {};
    int s = rp[row], e = rp[row + 1];
    for (int k = s + qw; k < e; k += 4) {
        uint2 a = cv[k];
        float va = __uint_as_float(a.y);
        u16x8 x = *(const u16x8*)(Xt + (size_t)a.x * NOUT + l * 8);
        #pragma unroll
        for (int i = 0; i < 8; ++i)
            acc[i] = fmaf(va, b2f(x[i]), acc[i]);
    }
    #pragma unroll
    for (int i = 0; i < 8; ++i) {
        float v = acc[i];
        v += __shfl_xor(v, 32);
        v += __shfl_xor(v, 16);
        v += bias[l * 8 + i];
        acc[i] = RELU ? fmaxf(v, 0.f) : v;
    }
    if (qw == 0) {
        u16x8 o;
        #pragma unroll
        for (int i = 0; i < 8; ++i) o[i] = f2b(acc[i]);
        *(u16x8*)(Out + ((size_t)tl * N_NODES + row) * NOUT + l * 8) = o;
    }
}

// ---------------------------------------------------------------------------
// bf16 MFMA GEMM: C[M,Nc] = A[M,K] @ B^T (+bias), out bf16. tile 64x128.
// ---------------------------------------------------------------------------
template<int KC, bool BIAS>
__global__ __launch_bounds__(256) void k_mgemm(
        const u16* __restrict__ A, const u16* __restrict__ B, int ldb,
        const float* __restrict__ bias, u16* __restrict__ C, int ldc, int M) {
    constexpr int K = KC * 32;
    __shared__ bf16x8 frag[8 * KC * 64];
    int tid = threadIdx.x, lane = tid & 63, wave = tid >> 6;
    int m0 = blockIdx.y * 64, n0 = blockIdx.x * 128;

    for (int f = wave; f < 8 * KC; f += 4) {
        int nl = f / KC, kc = f % KC;
        frag[f * 64 + lane] = *(const bf16x8*)(B + (size_t)(n0 + nl * 16 + (lane & 15)) * ldb
                                               + kc * 32 + ((lane >> 4) << 3));
    }
    __syncthreads();

    int arow = m0 + wave * 16 + (lane & 15);
    bool rowok = arow < M;
    const u16* ap = A + (size_t)arow * K + ((lane >> 4) << 3);
    bf16x8 zf = {0, 0, 0, 0, 0, 0, 0, 0};
    bf16x8 af[KC];
    #pragma unroll
    for (int kc = 0; kc < KC; ++kc)
        af[kc] = rowok ? *(const bf16x8*)(ap + kc * 32) : zf;

    f32x4 acc[8] = {};
    #pragma unroll
    for (int kc = 0; kc < KC; ++kc)
        #pragma unroll
        for (int nl = 0; nl < 8; ++nl)
            acc[nl] = __builtin_amdgcn_mfma_f32_16x16x32_bf16(
                af[kc], frag[(nl * KC + kc) * 64 + lane], acc[nl], 0, 0, 0);

    int r0 = m0 + wave * 16 + ((lane >> 4) << 2);
    #pragma unroll
    for (int nl = 0; nl < 8; ++nl) {
        int col = n0 + nl * 16 + (lane & 15);
        float bv = BIAS ? bias[col] : 0.f;
        #pragma unroll
        for (int r = 0; r < 4; ++r) {
            int row = r0 + r;
            if (row < M) C[(size_t)row * ldc + col] = f2b(acc[nl][r] + bv);
        }
    }
}

// ---------------------------------------------------------------------------
// Path A sequential GRU step: gh = h @ Bg_h^T (K=128, N=384 interleaved),
// epilogue reads precomputed GI (bf16, incl. b_ih) and does GRU pointwise.
// tile 64 x 192, grid (2, 313).
// ---------------------------------------------------------------------------
__global__ __launch_bounds__(256) void k_gru2(
        const u16* __restrict__ HbfIn, const u16* __restrict__ Bg_h,
        const float* __restrict__ bgh, const u16* __restrict__ GI_t,
        float* __restrict__ H, u16* __restrict__ HbfOut) {
    __shared__ bf16x8 frag[48 * 64];
    int tid = threadIdx.x, lane = tid & 63, wave = tid >> 6;
    int m0 = blockIdx.y * 64, n0 = blockIdx.x * 192;

    for (int f = wave; f < 48; f += 4) {
        int nl = f >> 2, kc = f & 3;
        frag[f * 64 + lane] = *(const bf16x8*)(Bg_h + (size_t)(n0 + nl * 16 + (lane & 15)) * 128
                                               + kc * 32 + ((lane >> 4) << 3));
    }
    __syncthreads();

    int arow = m0 + wave * 16 + (lane & 15);
    bool rowok = arow < N_NODES;
    bf16x8 zf = {0, 0, 0, 0, 0, 0, 0, 0};
    const u16* ap = HbfIn + (size_t)arow * 128 + ((lane >> 4) << 3);
    bf16x8 af[4];
    #pragma unroll
    for (int kc = 0; kc < 4; ++kc)
        af[kc] = rowok ? *(const bf16x8*)(ap + kc * 32) : zf;

    f32x4 acc[12] = {};
    #pragma unroll
    for (int kc = 0; kc < 4; ++kc)
        #pragma unroll
        for (int nl = 0; nl < 12; ++nl)
            acc[nl] = __builtin_amdgcn_mfma_f32_16x16x32_bf16(
                af[kc], frag[(nl * 4 + kc) * 64 + lane], acc[nl], 0, 0, 0);

    int r0 = m0 + wave * 16 + ((lane >> 4) << 2);
    int u = lane & 15;
    #pragma unroll
    for (int ub = 0; ub < 4; ++ub) {
        int cb = n0 + ub * 48;
        float br = bgh[cb + u], bz = bgh[cb + 16 + u], bn = bgh[cb + 32 + u];
        int jj = ((n0 / 48 + ub) << 4) + u;
        #pragma unroll
        for (int rr = 0; rr < 4; ++rr) {
            int row = r0 + rr;
            if (row >= N_NODES) continue;
            const u16* gi = GI_t + (size_t)row * 384 + cb;
            float gr = b2f(gi[u]), gz = b2f(gi[16 + u]), gn = b2f(gi[32 + u]);
            float rg = 1.f / (1.f + expf(-(gr + acc[ub * 3 + 0][rr] + br)));
            float zg = 1.f / (1.f + expf(-(gz + acc[ub * 3 + 1][rr] + bz)));
            float ng = tanhf(gn + rg * (acc[ub * 3 + 2][rr] + bn));
            size_t hidx = (size_t)row * HDIM + jj;
            float ho = H[hidx];
            float hn = (1.f - zg) * ng + zg * ho;
            H[hidx] = hn;
            HbfOut[hidx] = f2b(hn);
        }
    }
}

// ---------------------------------------------------------------------------
// Path B fused GRU step (K=256 over [X2_t | h]), 512-col interleave
// ---------------------------------------------------------------------------
__global__ __launch_bounds__(256) void k_gru_gemm(
        const u16* __restrict__ X2t, const u16* __restrict__ HbfIn,
        const u16* __restrict__ Bg, const float* __restrict__ bgb,
        float* __restrict__ H, u16* __restrict__ HbfOut) {
    __shared__ bf16x8 frag[64 * 64];
    int tid = threadIdx.x, lane = tid & 63, wave = tid >> 6;
    int m0 = blockIdx.y * 64, n0 = blockIdx.x * 128;

    for (int f = wave; f < 64; f += 4) {
        int nl = f >> 3, kc = f & 7;
        frag[f * 64 + lane] = *(const bf16x8*)(Bg + (size_t)(n0 + nl * 16 + (lane & 15)) * 256
                                               + kc * 32 + ((lane >> 4) << 3));
    }
    __syncthreads();

    int arow = m0 + wave * 16 + (lane & 15);
    bool rowok = arow < N_NODES;
    bf16x8 zf = {0, 0, 0, 0, 0, 0, 0, 0};
    const u16* a1 = X2t   + (size_t)arow * 128 + ((lane >> 4) << 3);
    const u16* a2 = HbfIn + (size_t)arow * 128 + ((lane >> 4) << 3);
    bf16x8 af[8];
    #pragma unroll
    for (int kc = 0; kc < 4; ++kc) af[kc]     = rowok ? *(const bf16x8*)(a1 + kc * 32) : zf;
    #pragma unroll
    for (int kc = 0; kc < 4; ++kc) af[4 + kc] = rowok ? *(const bf16x8*)(a2 + kc * 32) : zf;

    f32x4 acc[8] = {};
    #pragma unroll
    for (int kc = 0; kc < 8; ++kc)
        #pragma unroll
        for (int nl = 0; nl < 8; ++nl)
            acc[nl] = __builtin_amdgcn_mfma_f32_16x16x32_bf16(
                af[kc], frag[(nl * 8 + kc) * 64 + lane], acc[nl], 0, 0, 0);

    int rbase = m0 + wave * 16 + ((lane >> 4) << 2);
    #pragma unroll
    for (int hb = 0; hb < 2; ++hb) {
        int jj = (2 * blockIdx.x + hb) * 16 + (lane & 15);
        float br = bgb[n0 + (4 * hb + 0) * 16 + (lane & 15)];
        float bz = bgb[n0 + (4 * hb + 1) * 16 + (lane & 15)];
        float bi = bgb[n0 + (4 * hb + 2) * 16 + (lane & 15)];
        float bh = bgb[n0 + (4 * hb + 3) * 16 + (lane & 15)];
        #pragma unroll
        for (int r = 0; r < 4; ++r) {
            int row = rbase + r;
            if (row >= N_NODES) continue;
            float rg = acc[4 * hb + 0][r] + br;
            float zg = acc[4 * hb + 1][r] + bz;
            float ig = acc[4 * hb + 2][r] + bi;
            float hg = acc[4 * hb + 3][r] + bh;
            rg = 1.f / (1.f + expf(-rg));
            zg = 1.f / (1.f + expf(-zg));
            float ng = tanhf(ig + rg * hg);
            size_t idx = (size_t)row * HDIM + jj;
            float ho = H[idx];
            float hn = (1.f - zg) * ng + zg * ho;
            H[idx] = hn;
            HbfOut[idx] = f2b(hn);
        }
    }
}

// ---------------------------------------------------------------------------
// BatchNorm
// ---------------------------------------------------------------------------
__global__ void k_bnstats(const float* __restrict__ h, float* __restrict__ stats) {
    int j = threadIdx.x;
    int r0 = blockIdx.x * 200;
    float s = 0.f, sq = 0.f;
    for (int r = r0; r < r0 + 200; ++r) {
        float v = h[(size_t)r * HDIM + j];
        s += v; sq += v * v;
    }
    atomicAdd(&stats[j], s);
    atomicAdd(&stats[128 + j], sq);
}

__global__ void k_bnapply(const float* __restrict__ h, const float* __restrict__ stats,
                          const float* __restrict__ gamma, const float* __restrict__ beta,
                          u16* __restrict__ emb) {
    int i = blockIdx.x * 256 + threadIdx.x;
    if (i >= N_NODES * HDIM) return;
    int j = i & 127;
    float mean = stats[j] * (1.f / N_NODES);
    float var  = stats[128 + j] * (1.f / N_NODES) - mean * mean;
    emb[i] = f2b((h[i] - mean) * rsqrtf(var + BN_EPS) * gamma[j] + beta[j]);
}

// ---------------------------------------------------------------------------
// Edge predictor
// ---------------------------------------------------------------------------
__global__ __launch_bounds__(256) void k_edge(const int* __restrict__ edges,
        const u16* __restrict__ P, const u16* __restrict__ Q,
        const float* __restrict__ We2, const float* __restrict__ be2,
        float* __restrict__ out) {
    int e = blockIdx.x * 4 + (threadIdx.x >> 6);
    int lane = threadIdx.x & 63;
    if (e >= EP_EDGES) return;
    int u = edges[e];
    int v = edges[EP_EDGES + e];
    ushort4 pv = *(const ushort4*)(P + (size_t)u * NHID_E + lane * 4);
    ushort4 qv = *(const ushort4*)(Q + (size_t)v * NHID_E + lane * 4);
    const float4* w = (const float4*)(We2 + lane * 8);
    float4 w0 = w[0], w1 = w[1];
    float h0 = fmaxf(b2f(pv.x) + b2f(qv.x), 0.f);
    float h1 = fmaxf(b2f(pv.y) + b2f(qv.y), 0.f);
    float h2 = fmaxf(b2f(pv.z) + b2f(qv.z), 0.f);
    float h3 = fmaxf(b2f(pv.w) + b2f(qv.w), 0.f);
    float l0 = h0 * w0.x + h1 * w0.z + h2 * w1.x + h3 * w1.z;
    float l1 = h0 * w0.y + h1 * w0.w + h2 * w1.y + h3 * w1.w;
    #pragma unroll
    for (int off = 32; off > 0; off >>= 1) {
        l0 += __shfl_down(l0, off);
        l1 += __shfl_down(l1, off);
    }
    if (lane == 0) {
        l0 += be2[0]; l1 += be2[1];
        float m = fmaxf(l0, l1);
        float lse = m + logf(expf(l0 - m) + expf(l1 - m));
        out[(size_t)e * 2 + 0] = l0 - lse;
        out[(size_t)e * 2 + 1] = l1 - lse;
    }
}

// ---------------------------------------------------------------------------
extern "C" void kernel_launch(void* const* d_in, const int* in_sizes, int n_in,
                              void* d_out, int out_size, void* d_ws, size_t ws_size,
                              hipStream_t stream) {
    const int*   adj_rows = (const int*)  d_in[0];
    const int*   adj_cols = (const int*)  d_in[1];
    const float* adj_vals = (const float*)d_in[2];
    const int*   edges    = (const int*)  d_in[3];
    const float* W0   = (const float*)d_in[4];
    const float* b0   = (const float*)d_in[5];
    const float* W1   = (const float*)d_in[6];
    const float* b1   = (const float*)d_in[7];
    const float* W_ih = (const float*)d_in[8];
    const float* W_hh = (const float*)d_in[9];
    const float* b_ih = (const float*)d_in[10];
    const float* b_hh = (const float*)d_in[11];
    const float* gamma = (const float*)d_in[12];
    const float* beta  = (const float*)d_in[13];
    const float* We1  = (const float*)d_in[14];
    const float* be1  = (const float*)d_in[15];
    const float* We2  = (const float*)d_in[16];
    const float* be2  = (const float*)d_in[17];
    float* out = (float*)d_out;

    char* ws = (char*)d_ws;
    size_t off = 0;
    auto alloc = [&](size_t bytes) -> void* {
        void* p = ws + off;
        off += (bytes + 255) & ~(size_t)255;
        return p;
    };
    // ---- persistent ----
    int*   row_ptr = (int*)  alloc((size_t)T_SNAP * (N_NODES + 1) * 4);
    uint2* colval  = (uint2*)alloc((size_t)T_SNAP * E_EDGES * 8);
    u16*   W0_bf   = (u16*)  alloc((size_t)N_NODES * NHID * 2);
    u16*   W1t     = (u16*)  alloc((size_t)NOUT * NHID * 2);
    u16*   We1T    = (u16*)  alloc((size_t)NHID_E * 256 * 2);
    u16*   Bg_i    = (u16*)  alloc((size_t)384 * 128 * 2);
    u16*   Bg_h    = (u16*)  alloc((size_t)384 * 128 * 2);
    float* bgi     = (float*)alloc(384 * 4);
    float* bgh     = (float*)alloc(384 * 4);
    u16*   BgB     = (u16*)  alloc((size_t)512 * 256 * 2);
    float* bgbB    = (float*)alloc(512 * 4);
    float* h       = (float*)alloc((size_t)N_NODES * HDIM * 4);
    u16*   h_bfA   = (u16*)  alloc((size_t)N_NODES * HDIM * 2);
    u16*   h_bfB   = (u16*)  alloc((size_t)N_NODES * HDIM * 2);
    float* stats   = (float*)alloc(256 * 4);
    int*   bcnt    = (int*)  alloc((size_t)T_SNAP * NBUCK * 4);
    int*   bbase   = (int*)  alloc((size_t)T_SNAP * NBUCK * 4);
    int*   ovf_cnt = (int*)  alloc(256);
    size_t mark = off;

    // ---- union region: CSR phase ----
    off = mark;
    uint2* staging = (uint2*)alloc((size_t)T_SNAP * NBUCK * BCAP * 8);
    uint4* ovf     = (uint4*)alloc((size_t)T_SNAP * E_EDGES * 16);
    size_t csr_end = off;

    // ---- union region: compute phase ----
    const int BT = 4;
    off = mark;
    u16* X0_b = (u16*)alloc((size_t)BT * N_NODES * NHID * 2);
    u16* Y_b  = (u16*)alloc((size_t)BT * N_NODES * NOUT * 2);
    u16* X2_b = (u16*)alloc((size_t)BT * N_NODES * NOUT * 2);   // path A group buf
    u16* X2_all = (u16*)(ws + off);                              // path B alias (after X0/Y)
    size_t pathB_end = off + (((size_t)T_SNAP * N_NODES * NOUT * 2 + 255) & ~(size_t)255);
    u16* GI_all = (u16*)alloc((size_t)T_SNAP * N_NODES * 384 * 2);  // path A
    size_t pathA_end = off;

    // ---- union region: post phase ----
    off = mark;
    u16* emb = (u16*)alloc((size_t)N_NODES * HDIM * 2);
    u16* P   = (u16*)alloc((size_t)N_NODES * NHID_E * 2);
    u16* Q   = (u16*)alloc((size_t)N_NODES * NHID_E * 2);
    size_t post_end = off;

    bool pathA = (pathA_end + (16 << 20) <= ws_size);
    size_t need = csr_end;
    if (pathB_end > need) need = pathB_end;
    if (post_end  > need) need = post_end;
    if (pathA && pathA_end > need) need = pathA_end;
    if (need > ws_size) return;   // visible failure instead of corruption

    hipMemsetAsync(bcnt,    0, (size_t)T_SNAP * NBUCK * 4, stream);
    hipMemsetAsync(ovf_cnt, 0, 256, stream);
    hipMemsetAsync(stats,   0, 256 * 4, stream);
    hipMemsetAsync(h,       0, (size_t)N_NODES * HDIM * 4, stream);
    hipMemsetAsync(h_bfA,   0, (size_t)N_NODES * HDIM * 2, stream);

    // ---- CSR build v2 ----
    dim3 p1g((E_EDGES + 4095) / 4096, T_SNAP);
    k_p1   <<<p1g, 256, 0, stream>>>(adj_rows, adj_cols, adj_vals, bcnt, staging, ovf, ovf_cnt);
    k_bscan<<<1, 256, 0, stream>>>(bcnt, bbase, row_ptr);
    k_p2   <<<dim3(NBUCK, T_SNAP), 256, 0, stream>>>(bcnt, bbase, staging, ovf, ovf_cnt,
                                                     colval, row_ptr);

    // ---- weight conversions ----
    k_cvt       <<<(N_NODES * NHID / 4 + 255) / 256, 256, 0, stream>>>(W0, W0_bf, N_NODES * NHID / 4);
    k_tcvt      <<<(NHID * NOUT + 255) / 256,  256, 0, stream>>>(W1, W1t, NHID, NOUT);
    k_tcvt      <<<(256 * NHID_E + 255) / 256, 256, 0, stream>>>(We1, We1T, 256, NHID_E);
    if (pathA) {
        k_build_g3   <<<(384 * 128 + 255) / 256, 256, 0, stream>>>(W_ih, Bg_i);
        k_build_g3   <<<(384 * 128 + 255) / 256, 256, 0, stream>>>(W_hh, Bg_h);
        k_build_bias3<<<2, 256, 0, stream>>>(b_ih, b_hh, bgi, bgh);
    } else {
        k_build_bg <<<(512 * 256 + 255) / 256, 256, 0, stream>>>(W_ih, W_hh, BgB);
        k_build_bgb<<<2, 256, 0, stream>>>(b_ih, b_hh, bgbB);
    }

    // ---- batched GCN (+ GI precompute on path A) ----
    for (int g = 0; g < T_SNAP; g += BT) {
        k_spmm0<true><<<dim3(N_NODES / 4, BT), 256, 0, stream>>>(
            row_ptr, colval, g, W0_bf, b0, X0_b);
        int M = BT * N_NODES;
        k_mgemm<8, false><<<dim3(1, (M + 63) / 64), 256, 0, stream>>>(
            X0_b, W1t, NHID, nullptr, Y_b, NOUT, M);
        u16* x2dst = pathA ? X2_b : (X2_all + (size_t)g * N_NODES * NOUT);
        k_spmm1<false><<<dim3(N_NODES / 4, BT), 256, 0, stream>>>(
            row_ptr, colval, g, Y_b, (size_t)N_NODES * NOUT, b1, x2dst);
        if (pathA)
            k_mgemm<4, true><<<dim3(3, (M + 63) / 64), 256, 0, stream>>>(
                X2_b, Bg_i, 128, bgi, GI_all + (size_t)g * N_NODES * 384, 384, M);
    }

    // ---- GRU over time ----
    for (int t = 0; t < T_SNAP; ++t) {
        const u16* hin  = (t & 1) ? h_bfB : h_bfA;
        u16*       hout = (t & 1) ? h_bfA : h_bfB;
        if (pathA)
            k_gru2<<<dim3(2, (N_NODES + 63) / 64), 256, 0, stream>>>(
                hin, Bg_h, bgh, GI_all + (size_t)t * N_NODES * 384, h, hout);
        else
            k_gru_gemm<<<dim3(4, (N_NODES + 63) / 64), 256, 0, stream>>>(
                X2_all + (size_t)t * N_NODES * NOUT, hin, BgB, bgbB, h, hout);
    }

    // ---- BatchNorm ----
    k_bnstats<<<100, 128, 0, stream>>>(h, stats);
    k_bnapply<<<(N_NODES * HDIM + 255) / 256, 256, 0, stream>>>(h, stats, gamma, beta, emb);

    // ---- Edge MLP precompute + predictor ----
    k_mgemm<4, true><<<dim3(2, (N_NODES + 63) / 64), 256, 0, stream>>>(
        emb, We1T, 256, be1, P, NHID_E, N_NODES);
    k_mgemm<4, false><<<dim3(2, (N_NODES + 63) / 64), 256, 0, stream>>>(
        emb, We1T + 128, 256, nullptr, Q, NHID_E, N_NODES);
    k_edge<<<(EP_EDGES + 3) / 4, 256, 0, stream>>>(edges, P, Q, We2, be2, out);
}